// Round 1
// baseline (637.389 us; speedup 1.0000x reference)
//
#include <hip/hip_runtime.h>
#include <float.h>

#define WAY   5
#define SHOT  5
#define DIM   640
#define KTOP  16
#define EPSN  1e-8f

// Kernel B geometry
#define B_BLOCKS  1024
#define B_THREADS 256
#define WPB       (B_THREADS / 64)        // waves per block = 4
#define NWAVES    (B_BLOCKS * WPB)        // 4096
#define CANDS     (NWAVES * KTOP)         // 65536 candidates per way

// ws layout (float-element offsets)
#define OFF_PROTO   0                         // [WAY][DIM] basic proto (l2norm of mean)
#define OFF_SIMSUP  (OFF_PROTO + WAY * DIM)   // [SHOT][WAY]
#define OFF_CANDV   (OFF_SIMSUP + 32)         // [WAY][CANDS] candidate values
#define OFF_CANDI   (OFF_CANDV + WAY * CANDS) // [WAY][CANDS] candidate indices (int)
#define OFF_PROTOW  (OFF_CANDI + WAY * CANDS) // [WAY][DIM] weighted, normalized proto

__device__ __forceinline__ float blockReduce256(float v, float* sred) {
#pragma unroll
  for (int off = 32; off >= 1; off >>= 1) v += __shfl_xor(v, off, 64);
  __syncthreads();
  if ((threadIdx.x & 63) == 0) sred[threadIdx.x >> 6] = v;
  __syncthreads();
  return sred[0] + sred[1] + sred[2] + sred[3];
}

// ---------------- Kernel A: basic proto + support sims --------------------
__global__ __launch_bounds__(256) void protoA_kernel(
    const float* __restrict__ support, float* __restrict__ ws) {
  const int w = blockIdx.x;
  const int tid = threadIdx.x;
  __shared__ float sred[4];

  float m[3];
  float n2 = 0.f;
#pragma unroll
  for (int c = 0; c < 3; ++c) {
    const int t = tid + 256 * c;
    float v = 0.f;
    if (t < DIM) {
#pragma unroll
      for (int s = 0; s < SHOT; ++s) v += support[(s * WAY + w) * DIM + t];
      v *= (1.0f / SHOT);
    }
    m[c] = v;
    n2 += v * v;
  }
  n2 = blockReduce256(n2, sred);
  const float inv = 1.0f / fmaxf(sqrtf(n2), EPSN);

#pragma unroll
  for (int c = 0; c < 3; ++c) {
    const int t = tid + 256 * c;
    if (t < DIM) ws[OFF_PROTO + w * DIM + t] = m[c] * inv;
  }

  // support sims: dot(l2norm(support_sw), proto_n_w)
  for (int s = 0; s < SHOT; ++s) {
    float dot = 0.f, sn2 = 0.f;
#pragma unroll
    for (int c = 0; c < 3; ++c) {
      const int t = tid + 256 * c;
      if (t < DIM) {
        const float sv = support[(s * WAY + w) * DIM + t];
        dot += sv * (m[c] * inv);
        sn2 += sv * sv;
      }
    }
    dot = blockReduce256(dot, sred);
    sn2 = blockReduce256(sn2, sred);
    if (tid == 0)
      ws[OFF_SIMSUP + s * WAY + w] = dot / fmaxf(sqrtf(sn2), EPSN);
  }
}

// ------------- Kernel B: stream memory, per-wave top-16 per way -----------
__global__ __launch_bounds__(B_THREADS) void simTopkB_kernel(
    const float* __restrict__ memory, const float* __restrict__ ws,
    float* __restrict__ candV, int* __restrict__ candI, int M) {
  const int tid  = threadIdx.x;
  const int lane = tid & 63;
  const int wib  = tid >> 6;
  const int waveId = blockIdx.x * WPB + wib;

  // proto fragments in registers: pr[w][k] covers elements 2*(lane+64k)..+1
  float2 pr[WAY][5];
#pragma unroll
  for (int w = 0; w < WAY; ++w)
#pragma unroll
    for (int k = 0; k < 5; ++k)
      pr[w][k] = *(const float2*)&ws[OFF_PROTO + w * DIM + 2 * (lane + 64 * k)];

  __shared__ float sV[WPB][WAY][KTOP];
  __shared__ int   sI[WPB][WAY][KTOP];
  for (int i = lane; i < WAY * KTOP; i += 64) {
    (&sV[wib][0][0])[i] = -FLT_MAX;
    (&sI[wib][0][0])[i] = 0;
  }
  __syncthreads();

  float minV[WAY];
#pragma unroll
  for (int w = 0; w < WAY; ++w) minV[w] = -FLT_MAX;

  const int rows = (M + NWAVES - 1) / NWAVES;
  const int m0 = waveId * rows;
  const int m1 = min(m0 + rows, M);

  for (int m = m0; m < m1; ++m) {
    const float* row = memory + (size_t)m * DIM;
    float n2 = 0.f;
    float dt[WAY] = {0.f, 0.f, 0.f, 0.f, 0.f};
#pragma unroll
    for (int k = 0; k < 5; ++k) {
      const float2 v = *(const float2*)&row[2 * (lane + 64 * k)];
      n2 += v.x * v.x + v.y * v.y;
#pragma unroll
      for (int w = 0; w < WAY; ++w)
        dt[w] += v.x * pr[w][k].x + v.y * pr[w][k].y;
    }
#pragma unroll
    for (int off = 32; off >= 1; off >>= 1) {
      n2 += __shfl_xor(n2, off, 64);
#pragma unroll
      for (int w = 0; w < WAY; ++w) dt[w] += __shfl_xor(dt[w], off, 64);
    }
    const float scale = 0.2f / fmaxf(sqrtf(n2), EPSN);
#pragma unroll
    for (int w = 0; w < WAY; ++w) {
      const float sim = dt[w] * scale;       // uniform across the wave
      if (sim > minV[w]) {                   // wave-uniform branch
        // all lanes perform identical LDS RMW (same values -> benign)
        int j = KTOP - 1;
        while (j > 0) {
          const float up = sV[wib][w][j - 1];
          if (up >= sim) break;
          sV[wib][w][j] = up;
          sI[wib][w][j] = sI[wib][w][j - 1];
          --j;
        }
        sV[wib][w][j] = sim;
        sI[wib][w][j] = SHOT + m;            // global concat index
        minV[w] = sV[wib][w][KTOP - 1];
      }
    }
  }

  // emit this wave's candidates
  for (int i = lane; i < WAY * KTOP; i += 64) {
    const int w = i / KTOP, k = i % KTOP;
    candV[(size_t)w * CANDS + waveId * KTOP + k] = sV[wib][w][k];
    candI[(size_t)w * CANDS + waveId * KTOP + k] = sI[wib][w][k];
  }
}

// ------- Kernel C: exact global top-16 per way + weighted prototype -------
__global__ __launch_bounds__(256) void topkProtoC_kernel(
    const float* __restrict__ support, const float* __restrict__ memory,
    float* __restrict__ ws, const float* __restrict__ candV,
    const int* __restrict__ candI, int M) {
  const int w = blockIdx.x;
  const int tid = threadIdx.x;

  // per-thread top-16 in registers (all indices compile-time after unroll)
  float lv[KTOP];
  int   li[KTOP];
#pragma unroll
  for (int k = 0; k < KTOP; ++k) { lv[k] = -FLT_MAX; li[k] = 0; }
  if (tid < SHOT) {  // support entries, weight 1.0, concat index = shot idx
    lv[0] = ws[OFF_SIMSUP + tid * WAY + w];
    li[0] = tid;
  }

  const float* cv = candV + (size_t)w * CANDS;
  const int*   ci = candI + (size_t)w * CANDS;
  for (int i = tid; i < CANDS; i += 256) {
    const float v = cv[i];
    if (v > lv[KTOP - 1]) {
      const int id = ci[i];
#pragma unroll
      for (int j = KTOP - 1; j >= 1; --j) {
        const float up = lv[j - 1];
        const int   ui = li[j - 1];
        const bool shift = (up < v);
        const float cur = lv[j];
        const int  curi = li[j];
        lv[j] = shift ? up : (cur < v ? v : cur);
        li[j] = shift ? ui : (cur < v ? id : curi);
      }
      if (lv[0] < v) { li[0] = id; lv[0] = v; }
    }
  }

  __shared__ float sLV[256][KTOP];
  __shared__ int   sLI[256][KTOP];
  __shared__ float outV[KTOP];
  __shared__ int   outI[KTOP];
  __shared__ float sWv[4];
  __shared__ int   sWi[4];
  __shared__ float sred[4];
#pragma unroll
  for (int k = 0; k < KTOP; ++k) { sLV[tid][k] = lv[k]; sLI[tid][k] = li[k]; }
  __syncthreads();

  int cursor = 0;
  for (int r = 0; r < KTOP; ++r) {
    float v = (cursor < KTOP) ? sLV[tid][cursor] : -FLT_MAX;
    int   t = tid;
#pragma unroll
    for (int off = 32; off >= 1; off >>= 1) {
      const float ov = __shfl_xor(v, off, 64);
      const int   ot = __shfl_xor(t, off, 64);
      if (ov > v) { v = ov; t = ot; }
    }
    __syncthreads();
    if ((tid & 63) == 0) { sWv[tid >> 6] = v; sWi[tid >> 6] = t; }
    __syncthreads();
    float bv = sWv[0]; int bt = sWi[0];
#pragma unroll
    for (int q = 1; q < 4; ++q)
      if (sWv[q] > bv) { bv = sWv[q]; bt = sWi[q]; }
    if (tid == bt) {
      outV[r] = sLV[tid][cursor];
      outI[r] = sLI[tid][cursor];
      ++cursor;
    }
  }
  __syncthreads();

  float sumW = 0.f;
#pragma unroll
  for (int k = 0; k < KTOP; ++k) sumW += outV[k];

  float pw[3];
  float n2 = 0.f;
#pragma unroll
  for (int c = 0; c < 3; ++c) {
    const int t = tid + 256 * c;
    float acc = 0.f;
    if (t < DIM) {
#pragma unroll
      for (int k = 0; k < KTOP; ++k) {
        const int gi = outI[k];
        const float* emb = (gi < SHOT)
            ? (support + (size_t)(gi * WAY + w) * DIM)
            : (memory + (size_t)(gi - SHOT) * DIM);
        acc += outV[k] * emb[t];
      }
      acc /= sumW;
    }
    pw[c] = acc;
    n2 += acc * acc;
  }
  n2 = blockReduce256(n2, sred);
  const float inv = 1.0f / fmaxf(sqrtf(n2), EPSN);
#pragma unroll
  for (int c = 0; c < 3; ++c) {
    const int t = tid + 256 * c;
    if (t < DIM) ws[OFF_PROTOW + w * DIM + t] = pw[c] * inv;
  }
}

// ---------------- Kernel D: logits = q . proto_n / T ----------------------
__global__ __launch_bounds__(64) void logitsD_kernel(
    const float* __restrict__ query, const float* __restrict__ ws,
    float* __restrict__ out) {
  const int q = blockIdx.x;   // 0..74 (flattened nq*way)
  const int p = blockIdx.y;   // 0..4
  const int lane = threadIdx.x;
  const float* qr = query + (size_t)q * DIM;
  const float* pn = ws + OFF_PROTOW + p * DIM;
  float acc = 0.f;
#pragma unroll
  for (int k = 0; k < 5; ++k) {
    const float2 a = *(const float2*)&qr[2 * (lane + 64 * k)];
    const float2 b = *(const float2*)&pn[2 * (lane + 64 * k)];
    acc += a.x * b.x + a.y * b.y;
  }
#pragma unroll
  for (int off = 32; off >= 1; off >>= 1) acc += __shfl_xor(acc, off, 64);
  if (lane == 0) out[q * WAY + p] = acc * (1.0f / 64.0f);
}

extern "C" void kernel_launch(void* const* d_in, const int* in_sizes, int n_in,
                              void* d_out, int out_size, void* d_ws, size_t ws_size,
                              hipStream_t stream) {
  const float* support = (const float*)d_in[0];
  const float* query   = (const float*)d_in[1];
  const float* memory  = (const float*)d_in[2];
  float* out = (float*)d_out;
  float* ws  = (float*)d_ws;
  const int M = in_sizes[2] / DIM;

  float* candV = ws + OFF_CANDV;
  int*   candI = (int*)(ws + OFF_CANDI);

  hipLaunchKernelGGL(protoA_kernel, dim3(WAY), dim3(256), 0, stream, support, ws);
  hipLaunchKernelGGL(simTopkB_kernel, dim3(B_BLOCKS), dim3(B_THREADS), 0, stream,
                     memory, ws, candV, candI, M);
  hipLaunchKernelGGL(topkProtoC_kernel, dim3(WAY), dim3(256), 0, stream,
                     support, memory, ws, candV, candI, M);
  hipLaunchKernelGGL(logitsD_kernel, dim3(75, WAY), dim3(64), 0, stream,
                     query, ws, out);
}

// Round 2
// 250.078 us; speedup vs baseline: 2.5488x; 2.5488x over previous
//
#include <hip/hip_runtime.h>
#include <float.h>

#define WAY   5
#define SHOT  5
#define DIM   640
#define KTOP  16
#define EPSN  1e-8f

// Kernel B geometry: 2048 blocks x 4 waves = 8192 waves (8/SIMD oversubscribed)
#define B_BLOCKS  2048
#define B_THREADS 256
#define B_WAVES   (B_BLOCKS * (B_THREADS / 64))

// Top-k reduction geometry
#define SEGS   32
#define CANDS  (SEGS * KTOP)   // 512 candidates per way

// ws layout (float-element offsets)
#define OFF_PROTO   0                          // [WAY][DIM] basic proto (l2norm of mean)
#define OFF_SIMSUP  (WAY * DIM)                // [SHOT][WAY] support sims (32 slots)
#define OFF_PROTOW  (OFF_SIMSUP + 32)          // [WAY][DIM] weighted normalized proto
#define OFF_CANDV   (OFF_PROTOW + WAY * DIM)   // [WAY][CANDS]
#define OFF_CANDI   (OFF_CANDV + WAY * CANDS)  // [WAY][CANDS] (int)
#define OFF_SIM     (OFF_CANDI + WAY * CANDS)  // [WAY][M] all memory sims (runtime M)

__device__ __forceinline__ float blockReduce256(float v, float* sred) {
#pragma unroll
  for (int off = 32; off >= 1; off >>= 1) v += __shfl_xor(v, off, 64);
  __syncthreads();
  if ((threadIdx.x & 63) == 0) sred[threadIdx.x >> 6] = v;
  __syncthreads();
  return sred[0] + sred[1] + sred[2] + sred[3];
}

// ---------------- Kernel A: basic proto + support sims --------------------
__global__ __launch_bounds__(256) void protoA_kernel(
    const float* __restrict__ support, float* __restrict__ ws) {
  const int w = blockIdx.x;
  const int tid = threadIdx.x;
  __shared__ float sred[4];

  float m[3];
  float n2 = 0.f;
#pragma unroll
  for (int c = 0; c < 3; ++c) {
    const int t = tid + 256 * c;
    float v = 0.f;
    if (t < DIM) {
#pragma unroll
      for (int s = 0; s < SHOT; ++s) v += support[(s * WAY + w) * DIM + t];
      v *= (1.0f / SHOT);
    }
    m[c] = v;
    n2 += v * v;
  }
  n2 = blockReduce256(n2, sred);
  const float inv = 1.0f / fmaxf(sqrtf(n2), EPSN);

#pragma unroll
  for (int c = 0; c < 3; ++c) {
    const int t = tid + 256 * c;
    if (t < DIM) ws[OFF_PROTO + w * DIM + t] = m[c] * inv;
  }

  for (int s = 0; s < SHOT; ++s) {
    float dot = 0.f, sn2 = 0.f;
#pragma unroll
    for (int c = 0; c < 3; ++c) {
      const int t = tid + 256 * c;
      if (t < DIM) {
        const float sv = support[(s * WAY + w) * DIM + t];
        dot += sv * (m[c] * inv);
        sn2 += sv * sv;
      }
    }
    dot = blockReduce256(dot, sred);
    sn2 = blockReduce256(sn2, sred);
    if (tid == 0)
      ws[OFF_SIMSUP + s * WAY + w] = dot / fmaxf(sqrtf(sn2), EPSN);
  }
}

// ------------- Kernel B: pure streaming sims (no top-k state) -------------
__global__ __launch_bounds__(B_THREADS) void simB_kernel(
    const float* __restrict__ memory, const float* __restrict__ ws,
    float* __restrict__ simAll, int M) {
  const int lane = threadIdx.x & 63;
  const int waveId = blockIdx.x * (B_THREADS / 64) + (threadIdx.x >> 6);

  // proto fragments in registers: 10 elems/lane, matching float4/float4/float2 row loads
  float4 pa[WAY], pb[WAY];
  float2 pc[WAY];
#pragma unroll
  for (int w = 0; w < WAY; ++w) {
    pa[w] = *(const float4*)&ws[OFF_PROTO + w * DIM + 4 * lane];
    pb[w] = *(const float4*)&ws[OFF_PROTO + w * DIM + 256 + 4 * lane];
    pc[w] = *(const float2*)&ws[OFF_PROTO + w * DIM + 512 + 2 * lane];
  }

  const int rows = (M + B_WAVES - 1) / B_WAVES;
  const int m0 = waveId * rows;
  const int m1 = min(m0 + rows, M);

  for (int m = m0; m < m1; ++m) {
    const float* row = memory + (size_t)m * DIM;
    const float4 a = *(const float4*)&row[4 * lane];
    const float4 b = *(const float4*)&row[256 + 4 * lane];
    const float2 c = *(const float2*)&row[512 + 2 * lane];

    float n2 = a.x * a.x + a.y * a.y + a.z * a.z + a.w * a.w
             + b.x * b.x + b.y * b.y + b.z * b.z + b.w * b.w
             + c.x * c.x + c.y * c.y;
    float dt[WAY];
#pragma unroll
    for (int w = 0; w < WAY; ++w) {
      dt[w] = a.x * pa[w].x + a.y * pa[w].y + a.z * pa[w].z + a.w * pa[w].w
            + b.x * pb[w].x + b.y * pb[w].y + b.z * pb[w].z + b.w * pb[w].w
            + c.x * pc[w].x + c.y * pc[w].y;
    }
#pragma unroll
    for (int off = 32; off >= 1; off >>= 1) {
      n2 += __shfl_xor(n2, off, 64);
#pragma unroll
      for (int w = 0; w < WAY; ++w) dt[w] += __shfl_xor(dt[w], off, 64);
    }
    const float scale = 0.2f / fmaxf(sqrtf(n2), EPSN);
    float v = dt[0] * scale;
    v = (lane == 1) ? dt[1] * scale : v;
    v = (lane == 2) ? dt[2] * scale : v;
    v = (lane == 3) ? dt[3] * scale : v;
    v = (lane == 4) ? dt[4] * scale : v;
    if (lane < WAY) simAll[(size_t)lane * M + m] = v;
  }
}

// -------- Kernel C1: per-(way,segment) partial top-16 over simAll ---------
__global__ __launch_bounds__(256) void topkC1_kernel(
    const float* __restrict__ simAll, float* __restrict__ candV,
    int* __restrict__ candI, int M) {
  const int w   = blockIdx.x / SEGS;
  const int seg = blockIdx.x % SEGS;
  const int tid = threadIdx.x;
  const int len = (M + SEGS - 1) / SEGS;
  const int i0 = seg * len;
  const int i1 = min(i0 + len, M);

  float lv[KTOP];
  int   li[KTOP];
#pragma unroll
  for (int k = 0; k < KTOP; ++k) { lv[k] = -FLT_MAX; li[k] = 0; }

  const float* sv = simAll + (size_t)w * M;
  for (int i = i0 + tid; i < i1; i += 256) {
    const float v = sv[i];
    if (v > lv[KTOP - 1]) {
      const int id = SHOT + i;
#pragma unroll
      for (int j = KTOP - 1; j >= 1; --j) {
        const float up = lv[j - 1];
        const int   ui = li[j - 1];
        const bool shift = (up < v);
        const float cur = lv[j];
        const int  curi = li[j];
        lv[j] = shift ? up : (cur < v ? v : cur);
        li[j] = shift ? ui : (cur < v ? id : curi);
      }
      if (lv[0] < v) { li[0] = id; lv[0] = v; }
    }
  }

  __shared__ float sLV[256][KTOP];
  __shared__ int   sLI[256][KTOP];
  __shared__ float sWv[4];
  __shared__ int   sWi[4];
#pragma unroll
  for (int k = 0; k < KTOP; ++k) { sLV[tid][k] = lv[k]; sLI[tid][k] = li[k]; }
  __syncthreads();

  int cursor = 0;
  for (int r = 0; r < KTOP; ++r) {
    float v = (cursor < KTOP) ? sLV[tid][cursor] : -FLT_MAX;
    int   t = tid;
#pragma unroll
    for (int off = 32; off >= 1; off >>= 1) {
      const float ov = __shfl_xor(v, off, 64);
      const int   ot = __shfl_xor(t, off, 64);
      if (ov > v) { v = ov; t = ot; }
    }
    __syncthreads();
    if ((tid & 63) == 0) { sWv[tid >> 6] = v; sWi[tid >> 6] = t; }
    __syncthreads();
    float bv = sWv[0]; int bt = sWi[0];
#pragma unroll
    for (int q = 1; q < 4; ++q)
      if (sWv[q] > bv) { bv = sWv[q]; bt = sWi[q]; }
    if (tid == bt) {
      candV[(size_t)(w * SEGS + seg) * KTOP + r] = sLV[tid][cursor];
      candI[(size_t)(w * SEGS + seg) * KTOP + r] = sLI[tid][cursor];
      ++cursor;
    }
    __syncthreads();
  }
}

// ------- Kernel C2: merge candidates + support -> top-16 -> prototype -----
__global__ __launch_bounds__(256) void topkProtoC2_kernel(
    const float* __restrict__ support, const float* __restrict__ memory,
    float* __restrict__ ws, const float* __restrict__ candV,
    const int* __restrict__ candI, int M) {
  const int w = blockIdx.x;
  const int tid = threadIdx.x;

  float lv[KTOP];
  int   li[KTOP];
#pragma unroll
  for (int k = 0; k < KTOP; ++k) { lv[k] = -FLT_MAX; li[k] = 0; }
  if (tid < SHOT) {  // support entries, weight 1.0, concat index = shot idx
    lv[0] = ws[OFF_SIMSUP + tid * WAY + w];
    li[0] = tid;
  }

  const float* cv = candV + (size_t)w * CANDS;
  const int*   ci = candI + (size_t)w * CANDS;
  for (int i = tid; i < CANDS; i += 256) {
    const float v = cv[i];
    if (v > lv[KTOP - 1]) {
      const int id = ci[i];
#pragma unroll
      for (int j = KTOP - 1; j >= 1; --j) {
        const float up = lv[j - 1];
        const int   ui = li[j - 1];
        const bool shift = (up < v);
        const float cur = lv[j];
        const int  curi = li[j];
        lv[j] = shift ? up : (cur < v ? v : cur);
        li[j] = shift ? ui : (cur < v ? id : curi);
      }
      if (lv[0] < v) { li[0] = id; lv[0] = v; }
    }
  }

  __shared__ float sLV[256][KTOP];
  __shared__ int   sLI[256][KTOP];
  __shared__ float outV[KTOP];
  __shared__ int   outI[KTOP];
  __shared__ float sWv[4];
  __shared__ int   sWi[4];
  __shared__ float sred[4];
#pragma unroll
  for (int k = 0; k < KTOP; ++k) { sLV[tid][k] = lv[k]; sLI[tid][k] = li[k]; }
  __syncthreads();

  int cursor = 0;
  for (int r = 0; r < KTOP; ++r) {
    float v = (cursor < KTOP) ? sLV[tid][cursor] : -FLT_MAX;
    int   t = tid;
#pragma unroll
    for (int off = 32; off >= 1; off >>= 1) {
      const float ov = __shfl_xor(v, off, 64);
      const int   ot = __shfl_xor(t, off, 64);
      if (ov > v) { v = ov; t = ot; }
    }
    __syncthreads();
    if ((tid & 63) == 0) { sWv[tid >> 6] = v; sWi[tid >> 6] = t; }
    __syncthreads();
    float bv = sWv[0]; int bt = sWi[0];
#pragma unroll
    for (int q = 1; q < 4; ++q)
      if (sWv[q] > bv) { bv = sWv[q]; bt = sWi[q]; }
    if (tid == bt) {
      outV[r] = sLV[tid][cursor];
      outI[r] = sLI[tid][cursor];
      ++cursor;
    }
    __syncthreads();
  }

  float sumW = 0.f;
#pragma unroll
  for (int k = 0; k < KTOP; ++k) sumW += outV[k];

  float pw[3];
  float n2 = 0.f;
#pragma unroll
  for (int c = 0; c < 3; ++c) {
    const int t = tid + 256 * c;
    float acc = 0.f;
    if (t < DIM) {
#pragma unroll
      for (int k = 0; k < KTOP; ++k) {
        const int gi = outI[k];
        const float* emb = (gi < SHOT)
            ? (support + (size_t)(gi * WAY + w) * DIM)
            : (memory + (size_t)(gi - SHOT) * DIM);
        acc += outV[k] * emb[t];
      }
      acc /= sumW;
    }
    pw[c] = acc;
    n2 += acc * acc;
  }
  n2 = blockReduce256(n2, sred);
  const float inv = 1.0f / fmaxf(sqrtf(n2), EPSN);
#pragma unroll
  for (int c = 0; c < 3; ++c) {
    const int t = tid + 256 * c;
    if (t < DIM) ws[OFF_PROTOW + w * DIM + t] = pw[c] * inv;
  }
}

// ---------------- Kernel D: logits = q . proto_n / T ----------------------
__global__ __launch_bounds__(64) void logitsD_kernel(
    const float* __restrict__ query, const float* __restrict__ ws,
    float* __restrict__ out) {
  const int q = blockIdx.x;   // 0..74 (flattened nq*way)
  const int p = blockIdx.y;   // 0..4
  const int lane = threadIdx.x;
  const float* qr = query + (size_t)q * DIM;
  const float* pn = ws + OFF_PROTOW + p * DIM;
  float acc = 0.f;
#pragma unroll
  for (int k = 0; k < 5; ++k) {
    const float2 a = *(const float2*)&qr[2 * (lane + 64 * k)];
    const float2 b = *(const float2*)&pn[2 * (lane + 64 * k)];
    acc += a.x * b.x + a.y * b.y;
  }
#pragma unroll
  for (int off = 32; off >= 1; off >>= 1) acc += __shfl_xor(acc, off, 64);
  if (lane == 0) out[q * WAY + p] = acc * (1.0f / 64.0f);
}

extern "C" void kernel_launch(void* const* d_in, const int* in_sizes, int n_in,
                              void* d_out, int out_size, void* d_ws, size_t ws_size,
                              hipStream_t stream) {
  const float* support = (const float*)d_in[0];
  const float* query   = (const float*)d_in[1];
  const float* memory  = (const float*)d_in[2];
  float* out = (float*)d_out;
  float* ws  = (float*)d_ws;
  const int M = in_sizes[2] / DIM;

  float* candV  = ws + OFF_CANDV;
  int*   candI  = (int*)(ws + OFF_CANDI);
  float* simAll = ws + OFF_SIM;

  hipLaunchKernelGGL(protoA_kernel, dim3(WAY), dim3(256), 0, stream, support, ws);
  hipLaunchKernelGGL(simB_kernel, dim3(B_BLOCKS), dim3(B_THREADS), 0, stream,
                     memory, ws, simAll, M);
  hipLaunchKernelGGL(topkC1_kernel, dim3(WAY * SEGS), dim3(256), 0, stream,
                     simAll, candV, candI, M);
  hipLaunchKernelGGL(topkProtoC2_kernel, dim3(WAY), dim3(256), 0, stream,
                     support, memory, ws, candV, candI, M);
  hipLaunchKernelGGL(logitsD_kernel, dim3(75, WAY), dim3(64), 0, stream,
                     query, ws, out);
}

// Round 3
// 231.954 us; speedup vs baseline: 2.7479x; 1.0781x over previous
//
#include <hip/hip_runtime.h>
#include <float.h>

#define WAY   5
#define SHOT  5
#define DIM   640
#define KTOP  16
#define EPSN  1e-8f

// Kernel B geometry
#define B_BLOCKS  2048
#define B_THREADS 256
#define B_WAVES   (B_BLOCKS * (B_THREADS / 64))

// Top-k reduction geometry
#define SEGS   32
#define CANDS  (SEGS * KTOP)   // 512 candidates per way

// ws layout (float-element offsets)
#define OFF_PROTO   0                          // [WAY][DIM] basic proto (l2norm of mean)
#define OFF_SIMSUP  (WAY * DIM)                // [SHOT][WAY] support sims (32 slots)
#define OFF_PROTOW  (OFF_SIMSUP + 32)          // [WAY][DIM] weighted normalized proto
#define OFF_CANDV   (OFF_PROTOW + WAY * DIM)   // [WAY][CANDS]
#define OFF_CANDI   (OFF_CANDV + WAY * CANDS)  // [WAY][CANDS] (int)
#define OFF_SIM     (OFF_CANDI + WAY * CANDS)  // [WAY][M] all memory sims (runtime M)

__device__ __forceinline__ float blockReduce256(float v, float* sred) {
#pragma unroll
  for (int off = 32; off >= 1; off >>= 1) v += __shfl_xor(v, off, 64);
  __syncthreads();
  if ((threadIdx.x & 63) == 0) sred[threadIdx.x >> 6] = v;
  __syncthreads();
  return sred[0] + sred[1] + sred[2] + sred[3];
}

// ---- DPP helpers: reduce within 16-lane rows, pure VALU (no DS pipe) -----
template <int CTRL>
__device__ __forceinline__ float dppMov(float x) {
  int r = __builtin_amdgcn_update_dpp(0, __builtin_bit_cast(int, x), CTRL, 0xF, 0xF, true);
  return __builtin_bit_cast(float, r);
}
__device__ __forceinline__ float rowReduce16(float v) {
  v += dppMov<0x128>(v);  // row_ror:8
  v += dppMov<0x124>(v);  // row_ror:4
  v += dppMov<0x122>(v);  // row_ror:2
  v += dppMov<0x121>(v);  // row_ror:1
  return v;               // every lane holds its 16-lane row total
}
// pair-merge across xor32: result lanes<32 = sum64(lo), lanes>=32 = sum64(hi) partials
__device__ __forceinline__ float mergePair32(float lo, float hi, int lane) {
  const float o = (lane & 32) ? lo : hi;     // what this lane sends
  const float recvd = __shfl_xor(o, 32, 64);
  const float base = (lane & 32) ? hi : lo;
  return base + recvd;
}
// pair-merge across xor16: (r02=[a|c], r13=[b|d]) -> quarters [a|b|c|d]
__device__ __forceinline__ float mergePair16(float r02, float r13, int lane) {
  const float o = (lane & 16) ? r02 : r13;
  const float recvd = __shfl_xor(o, 16, 64);
  const float base = (lane & 16) ? r13 : r02;
  return base + recvd;
}

__device__ __forceinline__ float2 f2fma(float2 a, float2 b, float2 c) {
  return make_float2(fmaf(a.x, b.x, c.x), fmaf(a.y, b.y, c.y));
}

// ---------------- Kernel A: basic proto + support sims --------------------
__global__ __launch_bounds__(256) void protoA_kernel(
    const float* __restrict__ support, float* __restrict__ ws) {
  const int w = blockIdx.x;
  const int tid = threadIdx.x;
  __shared__ float sred[4];

  float m[3];
  float n2 = 0.f;
#pragma unroll
  for (int c = 0; c < 3; ++c) {
    const int t = tid + 256 * c;
    float v = 0.f;
    if (t < DIM) {
#pragma unroll
      for (int s = 0; s < SHOT; ++s) v += support[(s * WAY + w) * DIM + t];
      v *= (1.0f / SHOT);
    }
    m[c] = v;
    n2 += v * v;
  }
  n2 = blockReduce256(n2, sred);
  const float inv = 1.0f / fmaxf(sqrtf(n2), EPSN);

#pragma unroll
  for (int c = 0; c < 3; ++c) {
    const int t = tid + 256 * c;
    if (t < DIM) ws[OFF_PROTO + w * DIM + t] = m[c] * inv;
  }

  for (int s = 0; s < SHOT; ++s) {
    float dot = 0.f, sn2 = 0.f;
#pragma unroll
    for (int c = 0; c < 3; ++c) {
      const int t = tid + 256 * c;
      if (t < DIM) {
        const float sv = support[(s * WAY + w) * DIM + t];
        dot += sv * (m[c] * inv);
        sn2 += sv * sv;
      }
    }
    dot = blockReduce256(dot, sred);
    sn2 = blockReduce256(sn2, sred);
    if (tid == 0)
      ws[OFF_SIMSUP + s * WAY + w] = dot / fmaxf(sqrtf(sn2), EPSN);
  }
}

// ------------- Kernel B: pure streaming sims, DPP-packed reduce -----------
__global__ __launch_bounds__(B_THREADS) void simB_kernel(
    const float* __restrict__ memory, const float* __restrict__ ws,
    float* __restrict__ simAll, int M) {
  const int lane = threadIdx.x & 63;
  const int waveId = blockIdx.x * (B_THREADS / 64) + (threadIdx.x >> 6);

  const int rows = (M + B_WAVES - 1) / B_WAVES;
  const int m0 = waveId * rows;
  const int m1 = min(m0 + rows, M);
  if (m0 >= M) return;

  // proto fragments in registers: 10 elems/lane
  float4 pa[WAY], pb[WAY];
  float2 pc[WAY];
#pragma unroll
  for (int w = 0; w < WAY; ++w) {
    pa[w] = *(const float4*)&ws[OFF_PROTO + w * DIM + 4 * lane];
    pb[w] = *(const float4*)&ws[OFF_PROTO + w * DIM + 256 + 4 * lane];
    pc[w] = *(const float2*)&ws[OFF_PROTO + w * DIM + 512 + 2 * lane];
  }

  // per-lane writer config: lanes {0,16,32,48} carry dt0..3 (from mm),
  // lane 1 carries dt4 (from r4n lower half)
  int wIdx = -1;
  if (lane == 0) wIdx = 0;
  else if (lane == 16) wIdx = 1;
  else if (lane == 32) wIdx = 2;
  else if (lane == 48) wIdx = 3;
  else if (lane == 1)  wIdx = 4;
  const bool writer = (wIdx >= 0);
  float* wptr = simAll + (writer ? (size_t)wIdx * M : (size_t)0);

  // software pipeline: preload row m0
  {
    const float* r = memory + (size_t)m0 * DIM;
    float4 A  = *(const float4*)&r[4 * lane];
    float4 Bv = *(const float4*)&r[256 + 4 * lane];
    float2 C  = *(const float2*)&r[512 + 2 * lane];

    for (int m = m0; m < m1; ++m) {
      // issue next row's loads first (clamped on last iter; store predicated)
      const int mn = (m + 1 < m1) ? (m + 1) : m;
      const float* rn = memory + (size_t)mn * DIM;
      const float4 An  = *(const float4*)&rn[4 * lane];
      const float4 Bn  = *(const float4*)&rn[256 + 4 * lane];
      const float2 Cn  = *(const float2*)&rn[512 + 2 * lane];

      // 6 partial sums per lane, float2 accumulators (pk-math friendly)
      const float2 alo = make_float2(A.x, A.y),  ahi = make_float2(A.z, A.w);
      const float2 blo = make_float2(Bv.x, Bv.y), bhi = make_float2(Bv.z, Bv.w);
      float2 s2 = f2fma(alo, alo, f2fma(ahi, ahi, make_float2(0.f, 0.f)));
      s2 = f2fma(blo, blo, s2);
      s2 = f2fma(bhi, bhi, s2);
      s2 = f2fma(C, C, s2);
      float dt[WAY];
#pragma unroll
      for (int w = 0; w < WAY; ++w) {
        float2 d2 = f2fma(alo, make_float2(pa[w].x, pa[w].y),
                    f2fma(ahi, make_float2(pa[w].z, pa[w].w), make_float2(0.f, 0.f)));
        d2 = f2fma(blo, make_float2(pb[w].x, pb[w].y), d2);
        d2 = f2fma(bhi, make_float2(pb[w].z, pb[w].w), d2);
        d2 = f2fma(C, pc[w], d2);
        dt[w] = d2.x + d2.y;
      }
      const float n2 = s2.x + s2.y;

      // packed reduction: 5 shuffles + DPP finishes (all-VALU)
      const float r02 = mergePair32(dt[0], dt[2], lane);
      const float r13 = mergePair32(dt[1], dt[3], lane);
      float r4n = mergePair32(dt[4], n2, lane);
      float mm = mergePair16(r02, r13, lane);     // quarters [dt0|dt1|dt2|dt3]
      r4n += __shfl_xor(r4n, 16, 64);             // halves [dt4 | n2]
      mm = rowReduce16(mm);
      r4n = rowReduce16(r4n);

      const float n2t = __builtin_bit_cast(
          float, __builtin_amdgcn_readlane(__builtin_bit_cast(int, r4n), 63));
      const float scale = 0.2f / fmaxf(sqrtf(n2t), EPSN);
      const float val = (lane == 1) ? r4n : mm;
      if (writer) wptr[m] = val * scale;

      A = An; Bv = Bn; C = Cn;
    }
  }
}

// -------- Kernel C1: per-(way,segment) partial top-16 over simAll ---------
__global__ __launch_bounds__(256) void topkC1_kernel(
    const float* __restrict__ simAll, float* __restrict__ candV,
    int* __restrict__ candI, int M) {
  const int w   = blockIdx.x / SEGS;
  const int seg = blockIdx.x % SEGS;
  const int tid = threadIdx.x;
  const int len = (M + SEGS - 1) / SEGS;
  const int i0 = seg * len;
  const int i1 = min(i0 + len, M);

  float lv[KTOP];
  int   li[KTOP];
#pragma unroll
  for (int k = 0; k < KTOP; ++k) { lv[k] = -FLT_MAX; li[k] = 0; }

  const float* sv = simAll + (size_t)w * M;
  for (int i = i0 + tid; i < i1; i += 256) {
    const float v = sv[i];
    if (v > lv[KTOP - 1]) {
      const int id = SHOT + i;
#pragma unroll
      for (int j = KTOP - 1; j >= 1; --j) {
        const float up = lv[j - 1];
        const int   ui = li[j - 1];
        const bool shift = (up < v);
        const float cur = lv[j];
        const int  curi = li[j];
        lv[j] = shift ? up : (cur < v ? v : cur);
        li[j] = shift ? ui : (cur < v ? id : curi);
      }
      if (lv[0] < v) { li[0] = id; lv[0] = v; }
    }
  }

  __shared__ float sLV[256][KTOP];
  __shared__ int   sLI[256][KTOP];
  __shared__ float sWv[4];
  __shared__ int   sWi[4];
#pragma unroll
  for (int k = 0; k < KTOP; ++k) { sLV[tid][k] = lv[k]; sLI[tid][k] = li[k]; }
  __syncthreads();

  int cursor = 0;
  for (int r = 0; r < KTOP; ++r) {
    float v = (cursor < KTOP) ? sLV[tid][cursor] : -FLT_MAX;
    int   t = tid;
#pragma unroll
    for (int off = 32; off >= 1; off >>= 1) {
      const float ov = __shfl_xor(v, off, 64);
      const int   ot = __shfl_xor(t, off, 64);
      if (ov > v) { v = ov; t = ot; }
    }
    __syncthreads();
    if ((tid & 63) == 0) { sWv[tid >> 6] = v; sWi[tid >> 6] = t; }
    __syncthreads();
    float bv = sWv[0]; int bt = sWi[0];
#pragma unroll
    for (int q = 1; q < 4; ++q)
      if (sWv[q] > bv) { bv = sWv[q]; bt = sWi[q]; }
    if (tid == bt) {
      candV[(size_t)(w * SEGS + seg) * KTOP + r] = sLV[tid][cursor];
      candI[(size_t)(w * SEGS + seg) * KTOP + r] = sLI[tid][cursor];
      ++cursor;
    }
    __syncthreads();
  }
}

// ------- Kernel C2: merge candidates + support -> top-16 -> prototype -----
__global__ __launch_bounds__(256) void topkProtoC2_kernel(
    const float* __restrict__ support, const float* __restrict__ memory,
    float* __restrict__ ws, const float* __restrict__ candV,
    const int* __restrict__ candI, int M) {
  const int w = blockIdx.x;
  const int tid = threadIdx.x;

  float lv[KTOP];
  int   li[KTOP];
#pragma unroll
  for (int k = 0; k < KTOP; ++k) { lv[k] = -FLT_MAX; li[k] = 0; }
  if (tid < SHOT) {
    lv[0] = ws[OFF_SIMSUP + tid * WAY + w];
    li[0] = tid;
  }

  const float* cv = candV + (size_t)w * CANDS;
  const int*   ci = candI + (size_t)w * CANDS;
  for (int i = tid; i < CANDS; i += 256) {
    const float v = cv[i];
    if (v > lv[KTOP - 1]) {
      const int id = ci[i];
#pragma unroll
      for (int j = KTOP - 1; j >= 1; --j) {
        const float up = lv[j - 1];
        const int   ui = li[j - 1];
        const bool shift = (up < v);
        const float cur = lv[j];
        const int  curi = li[j];
        lv[j] = shift ? up : (cur < v ? v : cur);
        li[j] = shift ? ui : (cur < v ? id : curi);
      }
      if (lv[0] < v) { li[0] = id; lv[0] = v; }
    }
  }

  __shared__ float sLV[256][KTOP];
  __shared__ int   sLI[256][KTOP];
  __shared__ float outV[KTOP];
  __shared__ int   outI[KTOP];
  __shared__ float sWv[4];
  __shared__ int   sWi[4];
  __shared__ float sred[4];
#pragma unroll
  for (int k = 0; k < KTOP; ++k) { sLV[tid][k] = lv[k]; sLI[tid][k] = li[k]; }
  __syncthreads();

  int cursor = 0;
  for (int r = 0; r < KTOP; ++r) {
    float v = (cursor < KTOP) ? sLV[tid][cursor] : -FLT_MAX;
    int   t = tid;
#pragma unroll
    for (int off = 32; off >= 1; off >>= 1) {
      const float ov = __shfl_xor(v, off, 64);
      const int   ot = __shfl_xor(t, off, 64);
      if (ov > v) { v = ov; t = ot; }
    }
    __syncthreads();
    if ((tid & 63) == 0) { sWv[tid >> 6] = v; sWi[tid >> 6] = t; }
    __syncthreads();
    float bv = sWv[0]; int bt = sWi[0];
#pragma unroll
    for (int q = 1; q < 4; ++q)
      if (sWv[q] > bv) { bv = sWv[q]; bt = sWi[q]; }
    if (tid == bt) {
      outV[r] = sLV[tid][cursor];
      outI[r] = sLI[tid][cursor];
      ++cursor;
    }
    __syncthreads();
  }

  float sumW = 0.f;
#pragma unroll
  for (int k = 0; k < KTOP; ++k) sumW += outV[k];

  float pw[3];
  float n2 = 0.f;
#pragma unroll
  for (int c = 0; c < 3; ++c) {
    const int t = tid + 256 * c;
    float acc = 0.f;
    if (t < DIM) {
#pragma unroll
      for (int k = 0; k < KTOP; ++k) {
        const int gi = outI[k];
        const float* emb = (gi < SHOT)
            ? (support + (size_t)(gi * WAY + w) * DIM)
            : (memory + (size_t)(gi - SHOT) * DIM);
        acc += outV[k] * emb[t];
      }
      acc /= sumW;
    }
    pw[c] = acc;
    n2 += acc * acc;
  }
  n2 = blockReduce256(n2, sred);
  const float inv = 1.0f / fmaxf(sqrtf(n2), EPSN);
#pragma unroll
  for (int c = 0; c < 3; ++c) {
    const int t = tid + 256 * c;
    if (t < DIM) ws[OFF_PROTOW + w * DIM + t] = pw[c] * inv;
  }
}

// ---------------- Kernel D: logits = q . proto_n / T ----------------------
__global__ __launch_bounds__(64) void logitsD_kernel(
    const float* __restrict__ query, const float* __restrict__ ws,
    float* __restrict__ out) {
  const int q = blockIdx.x;
  const int p = blockIdx.y;
  const int lane = threadIdx.x;
  const float* qr = query + (size_t)q * DIM;
  const float* pn = ws + OFF_PROTOW + p * DIM;
  float acc = 0.f;
#pragma unroll
  for (int k = 0; k < 5; ++k) {
    const float2 a = *(const float2*)&qr[2 * (lane + 64 * k)];
    const float2 b = *(const float2*)&pn[2 * (lane + 64 * k)];
    acc += a.x * b.x + a.y * b.y;
  }
#pragma unroll
  for (int off = 32; off >= 1; off >>= 1) acc += __shfl_xor(acc, off, 64);
  if (lane == 0) out[q * WAY + p] = acc * (1.0f / 64.0f);
}

extern "C" void kernel_launch(void* const* d_in, const int* in_sizes, int n_in,
                              void* d_out, int out_size, void* d_ws, size_t ws_size,
                              hipStream_t stream) {
  const float* support = (const float*)d_in[0];
  const float* query   = (const float*)d_in[1];
  const float* memory  = (const float*)d_in[2];
  float* out = (float*)d_out;
  float* ws  = (float*)d_ws;
  const int M = in_sizes[2] / DIM;

  float* candV  = ws + OFF_CANDV;
  int*   candI  = (int*)(ws + OFF_CANDI);
  float* simAll = ws + OFF_SIM;

  hipLaunchKernelGGL(protoA_kernel, dim3(WAY), dim3(256), 0, stream, support, ws);
  hipLaunchKernelGGL(simB_kernel, dim3(B_BLOCKS), dim3(B_THREADS), 0, stream,
                     memory, ws, simAll, M);
  hipLaunchKernelGGL(topkC1_kernel, dim3(WAY * SEGS), dim3(256), 0, stream,
                     simAll, candV, candI, M);
  hipLaunchKernelGGL(topkProtoC2_kernel, dim3(WAY), dim3(256), 0, stream,
                     support, memory, ws, candV, candI, M);
  hipLaunchKernelGGL(logitsD_kernel, dim3(75, WAY), dim3(64), 0, stream,
                     query, ws, out);
}

// Round 4
// 221.311 us; speedup vs baseline: 2.8801x; 1.0481x over previous
//
#include <hip/hip_runtime.h>
#include <float.h>

#define WAY   5
#define SHOT  5
#define DIM   640
#define KTOP  16
#define EPSN  1e-8f

// Kernel B geometry
#define B_BLOCKS  2048
#define B_THREADS 256
#define B_WAVES   (B_BLOCKS * (B_THREADS / 64))   // 8192

// Top-k reduction geometry
#define SEGS   32
#define CANDS  (SEGS * KTOP)   // 512 candidates per way

// ws layout (float-element offsets)
#define OFF_PROTO   0                          // [WAY][DIM]
#define OFF_SIMSUP  (WAY * DIM)                // [SHOT][WAY] (32 slots)
#define OFF_PROTOW  (OFF_SIMSUP + 32)          // [WAY][DIM]
#define OFF_CANDV   (OFF_PROTOW + WAY * DIM)   // [WAY][CANDS]
#define OFF_CANDI   (OFF_CANDV + WAY * CANDS)  // [WAY][CANDS] (int)
#define OFF_PART    (OFF_CANDI + WAY * CANDS)  // [M][24] quarter partials
// simAll [WAY][M] follows at OFF_PART + M*24 (runtime M)

__device__ __forceinline__ float blockReduce256(float v, float* sred) {
#pragma unroll
  for (int off = 32; off >= 1; off >>= 1) v += __shfl_xor(v, off, 64);
  __syncthreads();
  if ((threadIdx.x & 63) == 0) sred[threadIdx.x >> 6] = v;
  __syncthreads();
  return sred[0] + sred[1] + sred[2] + sred[3];
}

// ---- DPP: reduce within 16-lane rows, pure VALU ----
template <int CTRL>
__device__ __forceinline__ float dppMov(float x) {
  int r = __builtin_amdgcn_update_dpp(0, __builtin_bit_cast(int, x), CTRL, 0xF, 0xF, true);
  return __builtin_bit_cast(float, r);
}
__device__ __forceinline__ float rowReduce16(float v) {
  v += dppMov<0x128>(v);  // row_ror:8
  v += dppMov<0x124>(v);  // row_ror:4
  v += dppMov<0x122>(v);  // row_ror:2
  v += dppMov<0x121>(v);  // row_ror:1
  return v;               // every lane holds its 16-lane group total
}

__device__ __forceinline__ float2 f2fma(float2 a, float2 b, float2 c) {
  return make_float2(fmaf(a.x, b.x, c.x), fmaf(a.y, b.y, c.y));
}

// ---------------- Kernel A: basic proto + support sims --------------------
__global__ __launch_bounds__(256) void protoA_kernel(
    const float* __restrict__ support, float* __restrict__ ws) {
  const int w = blockIdx.x;
  const int tid = threadIdx.x;
  __shared__ float sred[4];

  float m[3];
  float n2 = 0.f;
#pragma unroll
  for (int c = 0; c < 3; ++c) {
    const int t = tid + 256 * c;
    float v = 0.f;
    if (t < DIM) {
#pragma unroll
      for (int s = 0; s < SHOT; ++s) v += support[(s * WAY + w) * DIM + t];
      v *= (1.0f / SHOT);
    }
    m[c] = v;
    n2 += v * v;
  }
  n2 = blockReduce256(n2, sred);
  const float inv = 1.0f / fmaxf(sqrtf(n2), EPSN);

#pragma unroll
  for (int c = 0; c < 3; ++c) {
    const int t = tid + 256 * c;
    if (t < DIM) ws[OFF_PROTO + w * DIM + t] = m[c] * inv;
  }

  for (int s = 0; s < SHOT; ++s) {
    float dot = 0.f, sn2 = 0.f;
#pragma unroll
    for (int c = 0; c < 3; ++c) {
      const int t = tid + 256 * c;
      if (t < DIM) {
        const float sv = support[(s * WAY + w) * DIM + t];
        dot += sv * (m[c] * inv);
        sn2 += sv * sv;
      }
    }
    dot = blockReduce256(dot, sred);
    sn2 = blockReduce256(sn2, sred);
    if (tid == 0)
      ws[OFF_SIMSUP + s * WAY + w] = dot / fmaxf(sqrtf(sn2), EPSN);
  }
}

// ---- Kernel B1: stream rows (grid-stride mapping), quarter-partials out ----
// No cross-lane DS ops, no scale math, no serial chain in the hot loop.
__global__ __launch_bounds__(B_THREADS) void simB1_kernel(
    const float* __restrict__ memory, const float* __restrict__ ws,
    float* __restrict__ partials, int M) {
  const int lane = threadIdx.x & 63;
  const int waveId = blockIdx.x * (B_THREADS / 64) + (threadIdx.x >> 6);
  if (waveId >= M) return;

  // proto fragments in registers: 10 elems/lane (50 VGPR)
  float4 pa[WAY], pb[WAY];
  float2 pc[WAY];
#pragma unroll
  for (int w = 0; w < WAY; ++w) {
    pa[w] = *(const float4*)&ws[OFF_PROTO + w * DIM + 4 * lane];
    pb[w] = *(const float4*)&ws[OFF_PROTO + w * DIM + 256 + 4 * lane];
    pc[w] = *(const float2*)&ws[OFF_PROTO + w * DIM + 512 + 2 * lane];
  }

  const int sub = lane & 15;           // which value (0..4 = dt, 5 = n2)
  const int qtr = lane >> 4;           // which 16-lane quarter
  const bool wr = (sub < 6);
  const int woff = qtr * 6 + sub;      // within-row partial slot

  // depth-2 lookahead rotation over grid-strided rows
  int mc = waveId;
  int mn = (mc + B_WAVES < M) ? mc + B_WAVES : mc;
  float4 A0 = *(const float4*)&memory[(size_t)mc * DIM + 4 * lane];
  float4 B0 = *(const float4*)&memory[(size_t)mc * DIM + 256 + 4 * lane];
  float2 C0 = *(const float2*)&memory[(size_t)mc * DIM + 512 + 2 * lane];
  float4 A1 = *(const float4*)&memory[(size_t)mn * DIM + 4 * lane];
  float4 B1 = *(const float4*)&memory[(size_t)mn * DIM + 256 + 4 * lane];
  float2 C1 = *(const float2*)&memory[(size_t)mn * DIM + 512 + 2 * lane];

#pragma unroll 3
  while (mc < M) {
    const int m2 = (mn + B_WAVES < M) ? mn + B_WAVES : mn;
    const float4 A2 = *(const float4*)&memory[(size_t)m2 * DIM + 4 * lane];
    const float4 B2 = *(const float4*)&memory[(size_t)m2 * DIM + 256 + 4 * lane];
    const float2 C2 = *(const float2*)&memory[(size_t)m2 * DIM + 512 + 2 * lane];

    // 6 per-lane partials via packed-friendly float2 FMAs
    const float2 alo = make_float2(A0.x, A0.y), ahi = make_float2(A0.z, A0.w);
    const float2 blo = make_float2(B0.x, B0.y), bhi = make_float2(B0.z, B0.w);
    float2 s2 = f2fma(alo, alo, f2fma(ahi, ahi, make_float2(0.f, 0.f)));
    s2 = f2fma(blo, blo, s2);
    s2 = f2fma(bhi, bhi, s2);
    s2 = f2fma(C0, C0, s2);
    float dt[WAY];
#pragma unroll
    for (int w = 0; w < WAY; ++w) {
      float2 d2 = f2fma(alo, make_float2(pa[w].x, pa[w].y),
                  f2fma(ahi, make_float2(pa[w].z, pa[w].w), make_float2(0.f, 0.f)));
      d2 = f2fma(blo, make_float2(pb[w].x, pb[w].y), d2);
      d2 = f2fma(bhi, make_float2(pb[w].z, pb[w].w), d2);
      d2 = f2fma(C0, pc[w], d2);
      dt[w] = d2.x + d2.y;
    }
    const float n2v = s2.x + s2.y;

    // 16-lane DPP reduction only (24 VALU adds, zero DS)
    const float r0 = rowReduce16(dt[0]);
    const float r1 = rowReduce16(dt[1]);
    const float r2 = rowReduce16(dt[2]);
    const float r3 = rowReduce16(dt[3]);
    const float r4 = rowReduce16(dt[4]);
    const float rn = rowReduce16(n2v);

    float val = r0;
    val = (sub == 1) ? r1 : val;
    val = (sub == 2) ? r2 : val;
    val = (sub == 3) ? r3 : val;
    val = (sub == 4) ? r4 : val;
    val = (sub == 5) ? rn : val;
    if (wr) partials[(size_t)mc * 24 + woff] = val;

    A0 = A1; B0 = B1; C0 = C1;
    A1 = A2; B1 = B2; C1 = C2;
    mc = mn;
    mn = m2;
    if (mc == m2 && mc != waveId) break;   // tail: no further rows
    if (mc == waveId && mn == mc) {        // single-row wave
      // compute happened above for the only row; but loop would recompute —
      // handled by the normal exit below since mc stays == mn.
    }
    if (mc >= M) break;
    if (mn == mc) {                        // last row pending: compute once more
      // fall through; next iteration computes row mc then exits via mc==m2 check
    }
  }
}

// ---- Kernel B2: sum quarters, scale, write simAll [WAY][M] ----
__global__ __launch_bounds__(256) void reduceB2_kernel(
    const float* __restrict__ partials, float* __restrict__ simAll, int M) {
  const int t = blockIdx.x * 256 + threadIdx.x;
  if (t >= M) return;
  const float4* p = (const float4*)(partials + (size_t)t * 24);
  const float4 x0 = p[0], x1 = p[1], x2 = p[2], x3 = p[3], x4 = p[4], x5 = p[5];
  // layout [q][val]: index q*6+v
  const float v0 = x0.x + x1.z + x3.x + x4.z;
  const float v1 = x0.y + x1.w + x3.y + x4.w;
  const float v2 = x0.z + x2.x + x3.z + x5.x;
  const float v3 = x0.w + x2.y + x3.w + x5.y;
  const float v4 = x1.x + x2.z + x4.x + x5.z;
  const float n2 = x1.y + x2.w + x4.y + x5.w;
  const float scale = 0.2f / fmaxf(sqrtf(n2), EPSN);
  simAll[(size_t)0 * M + t] = v0 * scale;
  simAll[(size_t)1 * M + t] = v1 * scale;
  simAll[(size_t)2 * M + t] = v2 * scale;
  simAll[(size_t)3 * M + t] = v3 * scale;
  simAll[(size_t)4 * M + t] = v4 * scale;
}

// -------- Kernel C1: per-(way,segment) partial top-16 over simAll ---------
__global__ __launch_bounds__(256) void topkC1_kernel(
    const float* __restrict__ simAll, float* __restrict__ candV,
    int* __restrict__ candI, int M) {
  const int w   = blockIdx.x / SEGS;
  const int seg = blockIdx.x % SEGS;
  const int tid = threadIdx.x;
  const int len = (M + SEGS - 1) / SEGS;
  const int i0 = seg * len;
  const int i1 = min(i0 + len, M);

  float lv[KTOP];
  int   li[KTOP];
#pragma unroll
  for (int k = 0; k < KTOP; ++k) { lv[k] = -FLT_MAX; li[k] = 0; }

  const float* sv = simAll + (size_t)w * M;
  for (int i = i0 + tid; i < i1; i += 256) {
    const float v = sv[i];
    if (v > lv[KTOP - 1]) {
      const int id = SHOT + i;
#pragma unroll
      for (int j = KTOP - 1; j >= 1; --j) {
        const float up = lv[j - 1];
        const int   ui = li[j - 1];
        const bool shift = (up < v);
        const float cur = lv[j];
        const int  curi = li[j];
        lv[j] = shift ? up : (cur < v ? v : cur);
        li[j] = shift ? ui : (cur < v ? id : curi);
      }
      if (lv[0] < v) { li[0] = id; lv[0] = v; }
    }
  }

  __shared__ float sLV[256][KTOP];
  __shared__ int   sLI[256][KTOP];
  __shared__ float sWv[4];
  __shared__ int   sWi[4];
#pragma unroll
  for (int k = 0; k < KTOP; ++k) { sLV[tid][k] = lv[k]; sLI[tid][k] = li[k]; }
  __syncthreads();

  int cursor = 0;
  for (int r = 0; r < KTOP; ++r) {
    float v = (cursor < KTOP) ? sLV[tid][cursor] : -FLT_MAX;
    int   t = tid;
#pragma unroll
    for (int off = 32; off >= 1; off >>= 1) {
      const float ov = __shfl_xor(v, off, 64);
      const int   ot = __shfl_xor(t, off, 64);
      if (ov > v) { v = ov; t = ot; }
    }
    __syncthreads();
    if ((tid & 63) == 0) { sWv[tid >> 6] = v; sWi[tid >> 6] = t; }
    __syncthreads();
    float bv = sWv[0]; int bt = sWi[0];
#pragma unroll
    for (int q = 1; q < 4; ++q)
      if (sWv[q] > bv) { bv = sWv[q]; bt = sWi[q]; }
    if (tid == bt) {
      candV[(size_t)(w * SEGS + seg) * KTOP + r] = sLV[tid][cursor];
      candI[(size_t)(w * SEGS + seg) * KTOP + r] = sLI[tid][cursor];
      ++cursor;
    }
    __syncthreads();
  }
}

// ------- Kernel C2: merge candidates + support -> top-16 -> prototype -----
__global__ __launch_bounds__(256) void topkProtoC2_kernel(
    const float* __restrict__ support, const float* __restrict__ memory,
    float* __restrict__ ws, const float* __restrict__ candV,
    const int* __restrict__ candI, int M) {
  const int w = blockIdx.x;
  const int tid = threadIdx.x;

  float lv[KTOP];
  int   li[KTOP];
#pragma unroll
  for (int k = 0; k < KTOP; ++k) { lv[k] = -FLT_MAX; li[k] = 0; }
  if (tid < SHOT) {
    lv[0] = ws[OFF_SIMSUP + tid * WAY + w];
    li[0] = tid;
  }

  const float* cv = candV + (size_t)w * CANDS;
  const int*   ci = candI + (size_t)w * CANDS;
  for (int i = tid; i < CANDS; i += 256) {
    const float v = cv[i];
    if (v > lv[KTOP - 1]) {
      const int id = ci[i];
#pragma unroll
      for (int j = KTOP - 1; j >= 1; --j) {
        const float up = lv[j - 1];
        const int   ui = li[j - 1];
        const bool shift = (up < v);
        const float cur = lv[j];
        const int  curi = li[j];
        lv[j] = shift ? up : (cur < v ? v : cur);
        li[j] = shift ? ui : (cur < v ? id : curi);
      }
      if (lv[0] < v) { li[0] = id; lv[0] = v; }
    }
  }

  __shared__ float sLV[256][KTOP];
  __shared__ int   sLI[256][KTOP];
  __shared__ float outV[KTOP];
  __shared__ int   outI[KTOP];
  __shared__ float sWv[4];
  __shared__ int   sWi[4];
  __shared__ float sred[4];
#pragma unroll
  for (int k = 0; k < KTOP; ++k) { sLV[tid][k] = lv[k]; sLI[tid][k] = li[k]; }
  __syncthreads();

  int cursor = 0;
  for (int r = 0; r < KTOP; ++r) {
    float v = (cursor < KTOP) ? sLV[tid][cursor] : -FLT_MAX;
    int   t = tid;
#pragma unroll
    for (int off = 32; off >= 1; off >>= 1) {
      const float ov = __shfl_xor(v, off, 64);
      const int   ot = __shfl_xor(t, off, 64);
      if (ov > v) { v = ov; t = ot; }
    }
    __syncthreads();
    if ((tid & 63) == 0) { sWv[tid >> 6] = v; sWi[tid >> 6] = t; }
    __syncthreads();
    float bv = sWv[0]; int bt = sWi[0];
#pragma unroll
    for (int q = 1; q < 4; ++q)
      if (sWv[q] > bv) { bv = sWv[q]; bt = sWi[q]; }
    if (tid == bt) {
      outV[r] = sLV[tid][cursor];
      outI[r] = sLI[tid][cursor];
      ++cursor;
    }
    __syncthreads();
  }

  float sumW = 0.f;
#pragma unroll
  for (int k = 0; k < KTOP; ++k) sumW += outV[k];

  float pw[3];
  float n2 = 0.f;
#pragma unroll
  for (int c = 0; c < 3; ++c) {
    const int t = tid + 256 * c;
    float acc = 0.f;
    if (t < DIM) {
#pragma unroll
      for (int k = 0; k < KTOP; ++k) {
        const int gi = outI[k];
        const float* emb = (gi < SHOT)
            ? (support + (size_t)(gi * WAY + w) * DIM)
            : (memory + (size_t)(gi - SHOT) * DIM);
        acc += outV[k] * emb[t];
      }
      acc /= sumW;
    }
    pw[c] = acc;
    n2 += acc * acc;
  }
  n2 = blockReduce256(n2, sred);
  const float inv = 1.0f / fmaxf(sqrtf(n2), EPSN);
#pragma unroll
  for (int c = 0; c < 3; ++c) {
    const int t = tid + 256 * c;
    if (t < DIM) ws[OFF_PROTOW + w * DIM + t] = pw[c] * inv;
  }
}

// ---------------- Kernel D: logits = q . proto_n / T ----------------------
__global__ __launch_bounds__(64) void logitsD_kernel(
    const float* __restrict__ query, const float* __restrict__ ws,
    float* __restrict__ out) {
  const int q = blockIdx.x;
  const int p = blockIdx.y;
  const int lane = threadIdx.x;
  const float* qr = query + (size_t)q * DIM;
  const float* pn = ws + OFF_PROTOW + p * DIM;
  float acc = 0.f;
#pragma unroll
  for (int k = 0; k < 5; ++k) {
    const float2 a = *(const float2*)&qr[2 * (lane + 64 * k)];
    const float2 b = *(const float2*)&pn[2 * (lane + 64 * k)];
    acc += a.x * b.x + a.y * b.y;
  }
#pragma unroll
  for (int off = 32; off >= 1; off >>= 1) acc += __shfl_xor(acc, off, 64);
  if (lane == 0) out[q * WAY + p] = acc * (1.0f / 64.0f);
}

extern "C" void kernel_launch(void* const* d_in, const int* in_sizes, int n_in,
                              void* d_out, int out_size, void* d_ws, size_t ws_size,
                              hipStream_t stream) {
  const float* support = (const float*)d_in[0];
  const float* query   = (const float*)d_in[1];
  const float* memory  = (const float*)d_in[2];
  float* out = (float*)d_out;
  float* ws  = (float*)d_ws;
  const int M = in_sizes[2] / DIM;

  float* candV    = ws + OFF_CANDV;
  int*   candI    = (int*)(ws + OFF_CANDI);
  float* partials = ws + OFF_PART;
  float* simAll   = ws + OFF_PART + (size_t)M * 24;

  hipLaunchKernelGGL(protoA_kernel, dim3(WAY), dim3(256), 0, stream, support, ws);
  hipLaunchKernelGGL(simB1_kernel, dim3(B_BLOCKS), dim3(B_THREADS), 0, stream,
                     memory, ws, partials, M);
  hipLaunchKernelGGL(reduceB2_kernel, dim3((M + 255) / 256), dim3(256), 0, stream,
                     partials, simAll, M);
  hipLaunchKernelGGL(topkC1_kernel, dim3(WAY * SEGS), dim3(256), 0, stream,
                     simAll, candV, candI, M);
  hipLaunchKernelGGL(topkProtoC2_kernel, dim3(WAY), dim3(256), 0, stream,
                     support, memory, ws, candV, candI, M);
  hipLaunchKernelGGL(logitsD_kernel, dim3(75, WAY), dim3(64), 0, stream,
                     query, ws, out);
}

// Round 5
// 220.396 us; speedup vs baseline: 2.8920x; 1.0042x over previous
//
#include <hip/hip_runtime.h>
#include <float.h>

#define WAY   5
#define SHOT  5
#define DIM   640
#define KTOP  16
#define EPSN  1e-8f

// Kernel B geometry
#define B_BLOCKS  2048
#define B_THREADS 256
#define WPB       (B_THREADS / 64)
#define B_WAVES   (B_BLOCKS * WPB)   // 8192

// Top-k reduction geometry
#define SEGS   32
#define CANDS  (SEGS * KTOP)   // 512 candidates per way

// ws layout (float-element offsets)
#define OFF_PROTO   0                          // [WAY][DIM]
#define OFF_SIMSUP  (WAY * DIM)                // [SHOT][WAY] (32 slots)
#define OFF_PROTOW  (OFF_SIMSUP + 32)          // [WAY][DIM]
#define OFF_CANDV   (OFF_PROTOW + WAY * DIM)   // [WAY][CANDS]
#define OFF_CANDI   (OFF_CANDV + WAY * CANDS)  // [WAY][CANDS] (int)
#define OFF_PART    (OFF_CANDI + WAY * CANDS)  // [M][24] quarter partials
// simAll [WAY][M] follows at OFF_PART + M*24 (runtime M)

__device__ __forceinline__ float blockReduce256(float v, float* sred) {
#pragma unroll
  for (int off = 32; off >= 1; off >>= 1) v += __shfl_xor(v, off, 64);
  __syncthreads();
  if ((threadIdx.x & 63) == 0) sred[threadIdx.x >> 6] = v;
  __syncthreads();
  return sred[0] + sred[1] + sred[2] + sred[3];
}

// ---- DPP: reduce within 16-lane rows, pure VALU ----
template <int CTRL>
__device__ __forceinline__ float dppMov(float x) {
  int r = __builtin_amdgcn_update_dpp(0, __builtin_bit_cast(int, x), CTRL, 0xF, 0xF, true);
  return __builtin_bit_cast(float, r);
}
__device__ __forceinline__ float rowReduce16(float v) {
  v += dppMov<0x128>(v);  // row_ror:8
  v += dppMov<0x124>(v);  // row_ror:4
  v += dppMov<0x122>(v);  // row_ror:2
  v += dppMov<0x121>(v);  // row_ror:1
  return v;               // every lane holds its 16-lane group total
}

__device__ __forceinline__ float2 f2fma(float2 a, float2 b, float2 c) {
  return make_float2(fmaf(a.x, b.x, c.x), fmaf(a.y, b.y, c.y));
}

// ---------------- Kernel A: basic proto + support sims --------------------
__global__ __launch_bounds__(256) void protoA_kernel(
    const float* __restrict__ support, float* __restrict__ ws) {
  const int w = blockIdx.x;
  const int tid = threadIdx.x;
  __shared__ float sred[4];

  float m[3];
  float n2 = 0.f;
#pragma unroll
  for (int c = 0; c < 3; ++c) {
    const int t = tid + 256 * c;
    float v = 0.f;
    if (t < DIM) {
#pragma unroll
      for (int s = 0; s < SHOT; ++s) v += support[(s * WAY + w) * DIM + t];
      v *= (1.0f / SHOT);
    }
    m[c] = v;
    n2 += v * v;
  }
  n2 = blockReduce256(n2, sred);
  const float inv = 1.0f / fmaxf(sqrtf(n2), EPSN);

#pragma unroll
  for (int c = 0; c < 3; ++c) {
    const int t = tid + 256 * c;
    if (t < DIM) ws[OFF_PROTO + w * DIM + t] = m[c] * inv;
  }

  for (int s = 0; s < SHOT; ++s) {
    float dot = 0.f, sn2 = 0.f;
#pragma unroll
    for (int c = 0; c < 3; ++c) {
      const int t = tid + 256 * c;
      if (t < DIM) {
        const float sv = support[(s * WAY + w) * DIM + t];
        dot += sv * (m[c] * inv);
        sn2 += sv * sv;
      }
    }
    dot = blockReduce256(dot, sred);
    sn2 = blockReduce256(sn2, sred);
    if (tid == 0)
      ws[OFF_SIMSUP + s * WAY + w] = dot / fmaxf(sqrtf(sn2), EPSN);
  }
}

// ---- Kernel B1: counted-loop depth-3 pipelined stream, quarter-partials ----
__global__ __launch_bounds__(B_THREADS) void simB1_kernel(
    const float* __restrict__ memory, const float* __restrict__ ws,
    float* __restrict__ partials, int M) {
  const int lane = threadIdx.x & 63;
  const int waveId = blockIdx.x * WPB + (threadIdx.x >> 6);
  const int cnt = (waveId < M) ? ((M - 1 - waveId) / B_WAVES + 1) : 0;
  if (cnt == 0) return;

  // proto fragments in registers: 10 elems/lane (50 VGPR)
  float4 pa[WAY], pb[WAY];
  float2 pc[WAY];
#pragma unroll
  for (int w = 0; w < WAY; ++w) {
    pa[w] = *(const float4*)&ws[OFF_PROTO + w * DIM + 4 * lane];
    pb[w] = *(const float4*)&ws[OFF_PROTO + w * DIM + 256 + 4 * lane];
    pc[w] = *(const float2*)&ws[OFF_PROTO + w * DIM + 512 + 2 * lane];
  }

  const int sub = lane & 15;           // 0..4 = dt way, 5 = n2
  const int qtr = lane >> 4;           // 16-lane quarter
  const bool wr = (sub < 6);
  const int woff = qtr * 6 + sub;

  const size_t rstride = (size_t)B_WAVES * DIM;       // elements between my rows
  const float* base = memory + (size_t)waveId * DIM;  // row k = base + k*rstride
  const int o1 = 4 * lane, o2 = 256 + 4 * lane, o3 = 512 + 2 * lane;
  const int kLast = cnt - 1;

  // prologue: preload rows k = 0,1,2 (clamped to kLast; duplicate reads benign)
  const float* p0r = base;
  const float* p1r = base + (size_t)min(1, kLast) * rstride;
  const float* p2r = base + (size_t)min(2, kLast) * rstride;
  float4 A0 = *(const float4*)(p0r + o1);
  float4 B0 = *(const float4*)(p0r + o2);
  float2 C0 = *(const float2*)(p0r + o3);
  float4 A1 = *(const float4*)(p1r + o1);
  float4 B1 = *(const float4*)(p1r + o2);
  float2 C1 = *(const float2*)(p1r + o3);
  float4 A2 = *(const float4*)(p2r + o1);
  float4 B2 = *(const float4*)(p2r + o2);
  float2 C2 = *(const float2*)(p2r + o3);

  size_t pout = (size_t)waveId * 24 + woff;
  const size_t poutStride = (size_t)B_WAVES * 24;

#pragma unroll 3
  for (int k = 0; k < cnt; ++k) {
    // prefetch row k+3 (clamped)
    const float* pf = base + (size_t)min(k + 3, kLast) * rstride;
    const float4 An = *(const float4*)(pf + o1);
    const float4 Bn = *(const float4*)(pf + o2);
    const float2 Cn = *(const float2*)(pf + o3);

    // compute row k from (A0,B0,C0)
    const float2 alo = make_float2(A0.x, A0.y), ahi = make_float2(A0.z, A0.w);
    const float2 blo = make_float2(B0.x, B0.y), bhi = make_float2(B0.z, B0.w);
    float2 s2 = f2fma(alo, alo, f2fma(ahi, ahi, make_float2(0.f, 0.f)));
    s2 = f2fma(blo, blo, s2);
    s2 = f2fma(bhi, bhi, s2);
    s2 = f2fma(C0, C0, s2);
    float dt[WAY];
#pragma unroll
    for (int w = 0; w < WAY; ++w) {
      float2 d2 = f2fma(alo, make_float2(pa[w].x, pa[w].y),
                  f2fma(ahi, make_float2(pa[w].z, pa[w].w), make_float2(0.f, 0.f)));
      d2 = f2fma(blo, make_float2(pb[w].x, pb[w].y), d2);
      d2 = f2fma(bhi, make_float2(pb[w].z, pb[w].w), d2);
      d2 = f2fma(C0, pc[w], d2);
      dt[w] = d2.x + d2.y;
    }
    const float n2v = s2.x + s2.y;

    // 16-lane DPP reductions (pure VALU, independent chains)
    const float r0 = rowReduce16(dt[0]);
    const float r1 = rowReduce16(dt[1]);
    const float r2 = rowReduce16(dt[2]);
    const float r3 = rowReduce16(dt[3]);
    const float r4 = rowReduce16(dt[4]);
    const float rn = rowReduce16(n2v);

    float val = r0;
    val = (sub == 1) ? r1 : val;
    val = (sub == 2) ? r2 : val;
    val = (sub == 3) ? r3 : val;
    val = (sub == 4) ? r4 : val;
    val = (sub == 5) ? rn : val;
    if (wr) partials[pout] = val;
    pout += poutStride;

    // rotate pipeline (static after unroll-3)
    A0 = A1; B0 = B1; C0 = C1;
    A1 = A2; B1 = B2; C1 = C2;
    A2 = An; B2 = Bn; C2 = Cn;
  }
}

// ---- Kernel B2: sum quarters, scale, write simAll [WAY][M] ----
__global__ __launch_bounds__(256) void reduceB2_kernel(
    const float* __restrict__ partials, float* __restrict__ simAll, int M) {
  const int t = blockIdx.x * 256 + threadIdx.x;
  if (t >= M) return;
  const float4* p = (const float4*)(partials + (size_t)t * 24);
  const float4 x0 = p[0], x1 = p[1], x2 = p[2], x3 = p[3], x4 = p[4], x5 = p[5];
  const float v0 = x0.x + x1.z + x3.x + x4.z;
  const float v1 = x0.y + x1.w + x3.y + x4.w;
  const float v2 = x0.z + x2.x + x3.z + x5.x;
  const float v3 = x0.w + x2.y + x3.w + x5.y;
  const float v4 = x1.x + x2.z + x4.x + x5.z;
  const float n2 = x1.y + x2.w + x4.y + x5.w;
  const float scale = 0.2f / fmaxf(sqrtf(n2), EPSN);
  simAll[(size_t)0 * M + t] = v0 * scale;
  simAll[(size_t)1 * M + t] = v1 * scale;
  simAll[(size_t)2 * M + t] = v2 * scale;
  simAll[(size_t)3 * M + t] = v3 * scale;
  simAll[(size_t)4 * M + t] = v4 * scale;
}

// -------- Kernel C1: per-(way,segment) partial top-16 over simAll ---------
__global__ __launch_bounds__(256) void topkC1_kernel(
    const float* __restrict__ simAll, float* __restrict__ candV,
    int* __restrict__ candI, int M) {
  const int w   = blockIdx.x / SEGS;
  const int seg = blockIdx.x % SEGS;
  const int tid = threadIdx.x;
  const int len = (M + SEGS - 1) / SEGS;
  const int i0 = seg * len;
  const int i1 = min(i0 + len, M);

  float lv[KTOP];
  int   li[KTOP];
#pragma unroll
  for (int k = 0; k < KTOP; ++k) { lv[k] = -FLT_MAX; li[k] = 0; }

  const float* sv = simAll + (size_t)w * M;
  for (int i = i0 + tid; i < i1; i += 256) {
    const float v = sv[i];
    if (v > lv[KTOP - 1]) {
      const int id = SHOT + i;
#pragma unroll
      for (int j = KTOP - 1; j >= 1; --j) {
        const float up = lv[j - 1];
        const int   ui = li[j - 1];
        const bool shift = (up < v);
        const float cur = lv[j];
        const int  curi = li[j];
        lv[j] = shift ? up : (cur < v ? v : cur);
        li[j] = shift ? ui : (cur < v ? id : curi);
      }
      if (lv[0] < v) { li[0] = id; lv[0] = v; }
    }
  }

  __shared__ float sLV[256][KTOP];
  __shared__ int   sLI[256][KTOP];
  __shared__ float sWv[4];
  __shared__ int   sWi[4];
#pragma unroll
  for (int k = 0; k < KTOP; ++k) { sLV[tid][k] = lv[k]; sLI[tid][k] = li[k]; }
  __syncthreads();

  int cursor = 0;
  for (int r = 0; r < KTOP; ++r) {
    float v = (cursor < KTOP) ? sLV[tid][cursor] : -FLT_MAX;
    int   t = tid;
#pragma unroll
    for (int off = 32; off >= 1; off >>= 1) {
      const float ov = __shfl_xor(v, off, 64);
      const int   ot = __shfl_xor(t, off, 64);
      if (ov > v) { v = ov; t = ot; }
    }
    __syncthreads();
    if ((tid & 63) == 0) { sWv[tid >> 6] = v; sWi[tid >> 6] = t; }
    __syncthreads();
    float bv = sWv[0]; int bt = sWi[0];
#pragma unroll
    for (int q = 1; q < 4; ++q)
      if (sWv[q] > bv) { bv = sWv[q]; bt = sWi[q]; }
    if (tid == bt) {
      candV[(size_t)(w * SEGS + seg) * KTOP + r] = sLV[tid][cursor];
      candI[(size_t)(w * SEGS + seg) * KTOP + r] = sLI[tid][cursor];
      ++cursor;
    }
    __syncthreads();
  }
}

// ------- Kernel C2: merge candidates + support -> top-16 -> prototype -----
__global__ __launch_bounds__(256) void topkProtoC2_kernel(
    const float* __restrict__ support, const float* __restrict__ memory,
    float* __restrict__ ws, const float* __restrict__ candV,
    const int* __restrict__ candI, int M) {
  const int w = blockIdx.x;
  const int tid = threadIdx.x;

  float lv[KTOP];
  int   li[KTOP];
#pragma unroll
  for (int k = 0; k < KTOP; ++k) { lv[k] = -FLT_MAX; li[k] = 0; }
  if (tid < SHOT) {
    lv[0] = ws[OFF_SIMSUP + tid * WAY + w];
    li[0] = tid;
  }

  const float* cv = candV + (size_t)w * CANDS;
  const int*   ci = candI + (size_t)w * CANDS;
  for (int i = tid; i < CANDS; i += 256) {
    const float v = cv[i];
    if (v > lv[KTOP - 1]) {
      const int id = ci[i];
#pragma unroll
      for (int j = KTOP - 1; j >= 1; --j) {
        const float up = lv[j - 1];
        const int   ui = li[j - 1];
        const bool shift = (up < v);
        const float cur = lv[j];
        const int  curi = li[j];
        lv[j] = shift ? up : (cur < v ? v : cur);
        li[j] = shift ? ui : (cur < v ? id : curi);
      }
      if (lv[0] < v) { li[0] = id; lv[0] = v; }
    }
  }

  __shared__ float sLV[256][KTOP];
  __shared__ int   sLI[256][KTOP];
  __shared__ float outV[KTOP];
  __shared__ int   outI[KTOP];
  __shared__ float sWv[4];
  __shared__ int   sWi[4];
  __shared__ float sred[4];
#pragma unroll
  for (int k = 0; k < KTOP; ++k) { sLV[tid][k] = lv[k]; sLI[tid][k] = li[k]; }
  __syncthreads();

  int cursor = 0;
  for (int r = 0; r < KTOP; ++r) {
    float v = (cursor < KTOP) ? sLV[tid][cursor] : -FLT_MAX;
    int   t = tid;
#pragma unroll
    for (int off = 32; off >= 1; off >>= 1) {
      const float ov = __shfl_xor(v, off, 64);
      const int   ot = __shfl_xor(t, off, 64);
      if (ov > v) { v = ov; t = ot; }
    }
    __syncthreads();
    if ((tid & 63) == 0) { sWv[tid >> 6] = v; sWi[tid >> 6] = t; }
    __syncthreads();
    float bv = sWv[0]; int bt = sWi[0];
#pragma unroll
    for (int q = 1; q < 4; ++q)
      if (sWv[q] > bv) { bv = sWv[q]; bt = sWi[q]; }
    if (tid == bt) {
      outV[r] = sLV[tid][cursor];
      outI[r] = sLI[tid][cursor];
      ++cursor;
    }
    __syncthreads();
  }

  float sumW = 0.f;
#pragma unroll
  for (int k = 0; k < KTOP; ++k) sumW += outV[k];

  float pw[3];
  float n2 = 0.f;
#pragma unroll
  for (int c = 0; c < 3; ++c) {
    const int t = tid + 256 * c;
    float acc = 0.f;
    if (t < DIM) {
#pragma unroll
      for (int k = 0; k < KTOP; ++k) {
        const int gi = outI[k];
        const float* emb = (gi < SHOT)
            ? (support + (size_t)(gi * WAY + w) * DIM)
            : (memory + (size_t)(gi - SHOT) * DIM);
        acc += outV[k] * emb[t];
      }
      acc /= sumW;
    }
    pw[c] = acc;
    n2 += acc * acc;
  }
  n2 = blockReduce256(n2, sred);
  const float inv = 1.0f / fmaxf(sqrtf(n2), EPSN);
#pragma unroll
  for (int c = 0; c < 3; ++c) {
    const int t = tid + 256 * c;
    if (t < DIM) ws[OFF_PROTOW + w * DIM + t] = pw[c] * inv;
  }
}

// ---------------- Kernel D: logits = q . proto_n / T ----------------------
__global__ __launch_bounds__(64) void logitsD_kernel(
    const float* __restrict__ query, const float* __restrict__ ws,
    float* __restrict__ out) {
  const int q = blockIdx.x;
  const int p = blockIdx.y;
  const int lane = threadIdx.x;
  const float* qr = query + (size_t)q * DIM;
  const float* pn = ws + OFF_PROTOW + p * DIM;
  float acc = 0.f;
#pragma unroll
  for (int k = 0; k < 5; ++k) {
    const float2 a = *(const float2*)&qr[2 * (lane + 64 * k)];
    const float2 b = *(const float2*)&pn[2 * (lane + 64 * k)];
    acc += a.x * b.x + a.y * b.y;
  }
#pragma unroll
  for (int off = 32; off >= 1; off >>= 1) acc += __shfl_xor(acc, off, 64);
  if (lane == 0) out[q * WAY + p] = acc * (1.0f / 64.0f);
}

extern "C" void kernel_launch(void* const* d_in, const int* in_sizes, int n_in,
                              void* d_out, int out_size, void* d_ws, size_t ws_size,
                              hipStream_t stream) {
  const float* support = (const float*)d_in[0];
  const float* query   = (const float*)d_in[1];
  const float* memory  = (const float*)d_in[2];
  float* out = (float*)d_out;
  float* ws  = (float*)d_ws;
  const int M = in_sizes[2] / DIM;

  float* candV    = ws + OFF_CANDV;
  int*   candI    = (int*)(ws + OFF_CANDI);
  float* partials = ws + OFF_PART;
  float* simAll   = ws + OFF_PART + (size_t)M * 24;

  hipLaunchKernelGGL(protoA_kernel, dim3(WAY), dim3(256), 0, stream, support, ws);
  hipLaunchKernelGGL(simB1_kernel, dim3(B_BLOCKS), dim3(B_THREADS), 0, stream,
                     memory, ws, partials, M);
  hipLaunchKernelGGL(reduceB2_kernel, dim3((M + 255) / 256), dim3(256), 0, stream,
                     partials, simAll, M);
  hipLaunchKernelGGL(topkC1_kernel, dim3(WAY * SEGS), dim3(256), 0, stream,
                     simAll, candV, candI, M);
  hipLaunchKernelGGL(topkProtoC2_kernel, dim3(WAY), dim3(256), 0, stream,
                     support, memory, ws, candV, candI, M);
  hipLaunchKernelGGL(logitsD_kernel, dim3(75, WAY), dim3(64), 0, stream,
                     query, ws, out);
}

// Round 6
// 202.292 us; speedup vs baseline: 3.1508x; 1.0895x over previous
//
#include <hip/hip_runtime.h>
#include <float.h>

#define WAY   5
#define SHOT  5
#define DIM   640
#define KTOP  16
#define EPSN  1e-8f

// Kernel B geometry: 4 rows per wave-tile, 16 lanes per row
#define B_BLOCKS  2048
#define B_THREADS 256
#define WPB       (B_THREADS / 64)
#define B_WAVES   (B_BLOCKS * WPB)          // 8192
#define ROWSTRIDE (B_WAVES * 4)             // rows consumed per grid sweep

// Top-k reduction geometry
#define SEGS   32
#define CANDS  (SEGS * KTOP)   // 512 candidates per way

// ws layout (float-element offsets)
#define OFF_PROTO   0                          // [WAY][DIM]
#define OFF_SIMSUP  (WAY * DIM)                // [SHOT][WAY] (32 slots)
#define OFF_PROTOW  (OFF_SIMSUP + 32)          // [WAY][DIM]
#define OFF_CANDV   (OFF_PROTOW + WAY * DIM)   // [WAY][CANDS]
#define OFF_CANDI   (OFF_CANDV + WAY * CANDS)  // [WAY][CANDS] (int)
#define OFF_SIM     (OFF_CANDI + WAY * CANDS)  // [WAY][M] sims (runtime M)

__device__ __forceinline__ float blockReduce256(float v, float* sred) {
#pragma unroll
  for (int off = 32; off >= 1; off >>= 1) v += __shfl_xor(v, off, 64);
  __syncthreads();
  if ((threadIdx.x & 63) == 0) sred[threadIdx.x >> 6] = v;
  __syncthreads();
  return sred[0] + sred[1] + sred[2] + sred[3];
}

// ---- DPP: reduce within 16-lane rows (DPP "row" = 16 lanes), pure VALU ----
template <int CTRL>
__device__ __forceinline__ float dppMov(float x) {
  int r = __builtin_amdgcn_update_dpp(0, __builtin_bit_cast(int, x), CTRL, 0xF, 0xF, true);
  return __builtin_bit_cast(float, r);
}
__device__ __forceinline__ float rowReduce16(float v) {
  v += dppMov<0x128>(v);  // row_ror:8
  v += dppMov<0x124>(v);  // row_ror:4
  v += dppMov<0x122>(v);  // row_ror:2
  v += dppMov<0x121>(v);  // row_ror:1
  return v;               // every lane in the 16-lane group holds the total
}

// ---------------- Kernel A: basic proto + support sims --------------------
__global__ __launch_bounds__(256) void protoA_kernel(
    const float* __restrict__ support, float* __restrict__ ws) {
  const int w = blockIdx.x;
  const int tid = threadIdx.x;
  __shared__ float sred[4];

  float m[3];
  float n2 = 0.f;
#pragma unroll
  for (int c = 0; c < 3; ++c) {
    const int t = tid + 256 * c;
    float v = 0.f;
    if (t < DIM) {
#pragma unroll
      for (int s = 0; s < SHOT; ++s) v += support[(s * WAY + w) * DIM + t];
      v *= (1.0f / SHOT);
    }
    m[c] = v;
    n2 += v * v;
  }
  n2 = blockReduce256(n2, sred);
  const float inv = 1.0f / fmaxf(sqrtf(n2), EPSN);

#pragma unroll
  for (int c = 0; c < 3; ++c) {
    const int t = tid + 256 * c;
    if (t < DIM) ws[OFF_PROTO + w * DIM + t] = m[c] * inv;
  }

  for (int s = 0; s < SHOT; ++s) {
    float dot = 0.f, sn2 = 0.f;
#pragma unroll
    for (int c = 0; c < 3; ++c) {
      const int t = tid + 256 * c;
      if (t < DIM) {
        const float sv = support[(s * WAY + w) * DIM + t];
        dot += sv * (m[c] * inv);
        sn2 += sv * sv;
      }
    }
    dot = blockReduce256(dot, sred);
    sn2 = blockReduce256(sn2, sred);
    if (tid == 0)
      ws[OFF_SIMSUP + s * WAY + w] = dot / fmaxf(sqrtf(sn2), EPSN);
  }
}

// ---- Kernel B1: 4 rows/wave, 16 lanes/row, proto in LDS, direct sim out ----
__global__ __launch_bounds__(B_THREADS) void simB1_kernel(
    const float* __restrict__ memory, const float* __restrict__ ws,
    float* __restrict__ simAll, int M) {
  __shared__ float sP[WAY * DIM];   // 12.8 KB
  for (int i = threadIdx.x; i < WAY * DIM / 4; i += B_THREADS)
    ((float4*)sP)[i] = ((const float4*)(ws + OFF_PROTO))[i];
  __syncthreads();

  const int lane = threadIdx.x & 63;
  const int sub  = lane & 15;          // element-chunk within row
  const int grp  = lane >> 4;          // which of the wave's 4 rows
  const int waveId = blockIdx.x * WPB + (threadIdx.x >> 6);
  const int colOff = sub * 4;

  for (int base = waveId * 4; base < M; base += ROWSTRIDE) {
    const int row = base + grp;
    const bool rowOk = (row < M);
    const size_t roff = (size_t)(rowOk ? row : (M - 1)) * DIM + colOff;

    float n2 = 0.f, d0 = 0.f, d1 = 0.f, d2 = 0.f, d3 = 0.f, d4 = 0.f;
#pragma unroll
    for (int it = 0; it < 10; ++it) {
      const float4 x  = *(const float4*)&memory[roff + it * 64];
      const float4 p0 = *(const float4*)&sP[0 * DIM + colOff + it * 64];
      const float4 p1 = *(const float4*)&sP[1 * DIM + colOff + it * 64];
      const float4 p2 = *(const float4*)&sP[2 * DIM + colOff + it * 64];
      const float4 p3 = *(const float4*)&sP[3 * DIM + colOff + it * 64];
      const float4 p4 = *(const float4*)&sP[4 * DIM + colOff + it * 64];
      n2 = fmaf(x.x, x.x, fmaf(x.y, x.y, fmaf(x.z, x.z, fmaf(x.w, x.w, n2))));
      d0 = fmaf(x.x, p0.x, fmaf(x.y, p0.y, fmaf(x.z, p0.z, fmaf(x.w, p0.w, d0))));
      d1 = fmaf(x.x, p1.x, fmaf(x.y, p1.y, fmaf(x.z, p1.z, fmaf(x.w, p1.w, d1))));
      d2 = fmaf(x.x, p2.x, fmaf(x.y, p2.y, fmaf(x.z, p2.z, fmaf(x.w, p2.w, d2))));
      d3 = fmaf(x.x, p3.x, fmaf(x.y, p3.y, fmaf(x.z, p3.z, fmaf(x.w, p3.w, d3))));
      d4 = fmaf(x.x, p4.x, fmaf(x.y, p4.y, fmaf(x.z, p4.z, fmaf(x.w, p4.w, d4))));
    }

    // 16-lane reductions (within this group's DPP row)
    const float r0 = rowReduce16(d0);
    const float r1 = rowReduce16(d1);
    const float r2 = rowReduce16(d2);
    const float r3 = rowReduce16(d3);
    const float r4 = rowReduce16(d4);
    const float rn = rowReduce16(n2);

    const float scale = 0.2f / fmaxf(sqrtf(rn), EPSN);
    float val = r0;
    val = (sub == 1) ? r1 : val;
    val = (sub == 2) ? r2 : val;
    val = (sub == 3) ? r3 : val;
    val = (sub == 4) ? r4 : val;
    if (rowOk && sub < WAY) simAll[(size_t)sub * M + row] = val * scale;
  }
}

// -------- Kernel C1: per-(way,segment) partial top-16 over simAll ---------
__global__ __launch_bounds__(256) void topkC1_kernel(
    const float* __restrict__ simAll, float* __restrict__ candV,
    int* __restrict__ candI, int M) {
  const int w   = blockIdx.x / SEGS;
  const int seg = blockIdx.x % SEGS;
  const int tid = threadIdx.x;
  const int len = (M + SEGS - 1) / SEGS;
  const int i0 = seg * len;
  const int i1 = min(i0 + len, M);

  float lv[KTOP];
  int   li[KTOP];
#pragma unroll
  for (int k = 0; k < KTOP; ++k) { lv[k] = -FLT_MAX; li[k] = 0; }

  const float* sv = simAll + (size_t)w * M;
  for (int i = i0 + tid; i < i1; i += 256) {
    const float v = sv[i];
    if (v > lv[KTOP - 1]) {
      const int id = SHOT + i;
#pragma unroll
      for (int j = KTOP - 1; j >= 1; --j) {
        const float up = lv[j - 1];
        const int   ui = li[j - 1];
        const bool shift = (up < v);
        const float cur = lv[j];
        const int  curi = li[j];
        lv[j] = shift ? up : (cur < v ? v : cur);
        li[j] = shift ? ui : (cur < v ? id : curi);
      }
      if (lv[0] < v) { li[0] = id; lv[0] = v; }
    }
  }

  __shared__ float sLV[256][KTOP];
  __shared__ int   sLI[256][KTOP];
  __shared__ float sWv[4];
  __shared__ int   sWi[4];
#pragma unroll
  for (int k = 0; k < KTOP; ++k) { sLV[tid][k] = lv[k]; sLI[tid][k] = li[k]; }
  __syncthreads();

  int cursor = 0;
  for (int r = 0; r < KTOP; ++r) {
    float v = (cursor < KTOP) ? sLV[tid][cursor] : -FLT_MAX;
    int   t = tid;
#pragma unroll
    for (int off = 32; off >= 1; off >>= 1) {
      const float ov = __shfl_xor(v, off, 64);
      const int   ot = __shfl_xor(t, off, 64);
      if (ov > v) { v = ov; t = ot; }
    }
    __syncthreads();
    if ((tid & 63) == 0) { sWv[tid >> 6] = v; sWi[tid >> 6] = t; }
    __syncthreads();
    float bv = sWv[0]; int bt = sWi[0];
#pragma unroll
    for (int q = 1; q < 4; ++q)
      if (sWv[q] > bv) { bv = sWv[q]; bt = sWi[q]; }
    if (tid == bt) {
      candV[(size_t)(w * SEGS + seg) * KTOP + r] = sLV[tid][cursor];
      candI[(size_t)(w * SEGS + seg) * KTOP + r] = sLI[tid][cursor];
      ++cursor;
    }
    __syncthreads();
  }
}

// ------- Kernel C2: merge candidates + support -> top-16 -> prototype -----
__global__ __launch_bounds__(256) void topkProtoC2_kernel(
    const float* __restrict__ support, const float* __restrict__ memory,
    float* __restrict__ ws, const float* __restrict__ candV,
    const int* __restrict__ candI, int M) {
  const int w = blockIdx.x;
  const int tid = threadIdx.x;

  float lv[KTOP];
  int   li[KTOP];
#pragma unroll
  for (int k = 0; k < KTOP; ++k) { lv[k] = -FLT_MAX; li[k] = 0; }
  if (tid < SHOT) {
    lv[0] = ws[OFF_SIMSUP + tid * WAY + w];
    li[0] = tid;
  }

  const float* cv = candV + (size_t)w * CANDS;
  const int*   ci = candI + (size_t)w * CANDS;
  for (int i = tid; i < CANDS; i += 256) {
    const float v = cv[i];
    if (v > lv[KTOP - 1]) {
      const int id = ci[i];
#pragma unroll
      for (int j = KTOP - 1; j >= 1; --j) {
        const float up = lv[j - 1];
        const int   ui = li[j - 1];
        const bool shift = (up < v);
        const float cur = lv[j];
        const int  curi = li[j];
        lv[j] = shift ? up : (cur < v ? v : cur);
        li[j] = shift ? ui : (cur < v ? id : curi);
      }
      if (lv[0] < v) { li[0] = id; lv[0] = v; }
    }
  }

  __shared__ float sLV[256][KTOP];
  __shared__ int   sLI[256][KTOP];
  __shared__ float outV[KTOP];
  __shared__ int   outI[KTOP];
  __shared__ float sWv[4];
  __shared__ int   sWi[4];
  __shared__ float sred[4];
#pragma unroll
  for (int k = 0; k < KTOP; ++k) { sLV[tid][k] = lv[k]; sLI[tid][k] = li[k]; }
  __syncthreads();

  int cursor = 0;
  for (int r = 0; r < KTOP; ++r) {
    float v = (cursor < KTOP) ? sLV[tid][cursor] : -FLT_MAX;
    int   t = tid;
#pragma unroll
    for (int off = 32; off >= 1; off >>= 1) {
      const float ov = __shfl_xor(v, off, 64);
      const int   ot = __shfl_xor(t, off, 64);
      if (ov > v) { v = ov; t = ot; }
    }
    __syncthreads();
    if ((tid & 63) == 0) { sWv[tid >> 6] = v; sWi[tid >> 6] = t; }
    __syncthreads();
    float bv = sWv[0]; int bt = sWi[0];
#pragma unroll
    for (int q = 1; q < 4; ++q)
      if (sWv[q] > bv) { bv = sWv[q]; bt = sWi[q]; }
    if (tid == bt) {
      outV[r] = sLV[tid][cursor];
      outI[r] = sLI[tid][cursor];
      ++cursor;
    }
    __syncthreads();
  }

  float sumW = 0.f;
#pragma unroll
  for (int k = 0; k < KTOP; ++k) sumW += outV[k];

  float pw[3];
  float n2 = 0.f;
#pragma unroll
  for (int c = 0; c < 3; ++c) {
    const int t = tid + 256 * c;
    float acc = 0.f;
    if (t < DIM) {
#pragma unroll
      for (int k = 0; k < KTOP; ++k) {
        const int gi = outI[k];
        const float* emb = (gi < SHOT)
            ? (support + (size_t)(gi * WAY + w) * DIM)
            : (memory + (size_t)(gi - SHOT) * DIM);
        acc += outV[k] * emb[t];
      }
      acc /= sumW;
    }
    pw[c] = acc;
    n2 += acc * acc;
  }
  n2 = blockReduce256(n2, sred);
  const float inv = 1.0f / fmaxf(sqrtf(n2), EPSN);
#pragma unroll
  for (int c = 0; c < 3; ++c) {
    const int t = tid + 256 * c;
    if (t < DIM) ws[OFF_PROTOW + w * DIM + t] = pw[c] * inv;
  }
}

// ---------------- Kernel D: logits = q . proto_n / T ----------------------
__global__ __launch_bounds__(64) void logitsD_kernel(
    const float* __restrict__ query, const float* __restrict__ ws,
    float* __restrict__ out) {
  const int q = blockIdx.x;
  const int p = blockIdx.y;
  const int lane = threadIdx.x;
  const float* qr = query + (size_t)q * DIM;
  const float* pn = ws + OFF_PROTOW + p * DIM;
  float acc = 0.f;
#pragma unroll
  for (int k = 0; k < 5; ++k) {
    const float2 a = *(const float2*)&qr[2 * (lane + 64 * k)];
    const float2 b = *(const float2*)&pn[2 * (lane + 64 * k)];
    acc += a.x * b.x + a.y * b.y;
  }
#pragma unroll
  for (int off = 32; off >= 1; off >>= 1) acc += __shfl_xor(acc, off, 64);
  if (lane == 0) out[q * WAY + p] = acc * (1.0f / 64.0f);
}

extern "C" void kernel_launch(void* const* d_in, const int* in_sizes, int n_in,
                              void* d_out, int out_size, void* d_ws, size_t ws_size,
                              hipStream_t stream) {
  const float* support = (const float*)d_in[0];
  const float* query   = (const float*)d_in[1];
  const float* memory  = (const float*)d_in[2];
  float* out = (float*)d_out;
  float* ws  = (float*)d_ws;
  const int M = in_sizes[2] / DIM;

  float* candV  = ws + OFF_CANDV;
  int*   candI  = (int*)(ws + OFF_CANDI);
  float* simAll = ws + OFF_SIM;

  hipLaunchKernelGGL(protoA_kernel, dim3(WAY), dim3(256), 0, stream, support, ws);
  hipLaunchKernelGGL(simB1_kernel, dim3(B_BLOCKS), dim3(B_THREADS), 0, stream,
                     memory, ws, simAll, M);
  hipLaunchKernelGGL(topkC1_kernel, dim3(WAY * SEGS), dim3(256), 0, stream,
                     simAll, candV, candI, M);
  hipLaunchKernelGGL(topkProtoC2_kernel, dim3(WAY), dim3(256), 0, stream,
                     support, memory, ws, candV, candI, M);
  hipLaunchKernelGGL(logitsD_kernel, dim3(75, WAY), dim3(64), 0, stream,
                     query, ws, out);
}

// Round 7
// 198.901 us; speedup vs baseline: 3.2046x; 1.0170x over previous
//
#include <hip/hip_runtime.h>
#include <float.h>

#define WAY   5
#define SHOT  5
#define DIM   640
#define KTOP  16
#define EPSN  1e-8f

// Kernel B geometry: 8 rows per wave-iter (2 sets of 4 rows x 16 lanes)
#define B_BLOCKS  1024
#define B_THREADS 256
#define WPB       (B_THREADS / 64)
#define B_WAVES   (B_BLOCKS * WPB)          // 4096
#define RPI       8                          // rows per wave per iteration
#define ROWSTRIDE (B_WAVES * RPI)            // 32768 rows per sweep

// Top-k reduction geometry
#define SEGS   32
#define CANDS  (SEGS * KTOP)   // 512 candidates per way

// ws layout (float-element offsets)
#define OFF_PROTO   0                          // [WAY][DIM]
#define OFF_SIMSUP  (WAY * DIM)                // [SHOT][WAY] (32 slots)
#define OFF_PROTOW  (OFF_SIMSUP + 32)          // [WAY][DIM]
#define OFF_CANDV   (OFF_PROTOW + WAY * DIM)   // [WAY][CANDS]
#define OFF_CANDI   (OFF_CANDV + WAY * CANDS)  // [WAY][CANDS] (int)
#define OFF_SIM     (OFF_CANDI + WAY * CANDS)  // [WAY][M] sims (runtime M)

__device__ __forceinline__ float blockReduce256(float v, float* sred) {
#pragma unroll
  for (int off = 32; off >= 1; off >>= 1) v += __shfl_xor(v, off, 64);
  __syncthreads();
  if ((threadIdx.x & 63) == 0) sred[threadIdx.x >> 6] = v;
  __syncthreads();
  return sred[0] + sred[1] + sred[2] + sred[3];
}

// ---- DPP: reduce within 16-lane groups, pure VALU ----
template <int CTRL>
__device__ __forceinline__ float dppMov(float x) {
  int r = __builtin_amdgcn_update_dpp(0, __builtin_bit_cast(int, x), CTRL, 0xF, 0xF, true);
  return __builtin_bit_cast(float, r);
}
__device__ __forceinline__ float rowReduce16(float v) {
  v += dppMov<0x128>(v);  // row_ror:8
  v += dppMov<0x124>(v);  // row_ror:4
  v += dppMov<0x122>(v);  // row_ror:2
  v += dppMov<0x121>(v);  // row_ror:1
  return v;               // every lane in the 16-lane group holds the total
}

// ---------------- Kernel A: basic proto + support sims --------------------
__global__ __launch_bounds__(256) void protoA_kernel(
    const float* __restrict__ support, float* __restrict__ ws) {
  const int w = blockIdx.x;
  const int tid = threadIdx.x;
  __shared__ float sred[4];

  float m[3];
  float n2 = 0.f;
#pragma unroll
  for (int c = 0; c < 3; ++c) {
    const int t = tid + 256 * c;
    float v = 0.f;
    if (t < DIM) {
#pragma unroll
      for (int s = 0; s < SHOT; ++s) v += support[(s * WAY + w) * DIM + t];
      v *= (1.0f / SHOT);
    }
    m[c] = v;
    n2 += v * v;
  }
  n2 = blockReduce256(n2, sred);
  const float inv = 1.0f / fmaxf(sqrtf(n2), EPSN);

#pragma unroll
  for (int c = 0; c < 3; ++c) {
    const int t = tid + 256 * c;
    if (t < DIM) ws[OFF_PROTO + w * DIM + t] = m[c] * inv;
  }

  for (int s = 0; s < SHOT; ++s) {
    float dot = 0.f, sn2 = 0.f;
#pragma unroll
    for (int c = 0; c < 3; ++c) {
      const int t = tid + 256 * c;
      if (t < DIM) {
        const float sv = support[(s * WAY + w) * DIM + t];
        dot += sv * (m[c] * inv);
        sn2 += sv * sv;
      }
    }
    dot = blockReduce256(dot, sred);
    sn2 = blockReduce256(sn2, sred);
    if (tid == 0)
      ws[OFF_SIMSUP + s * WAY + w] = dot / fmaxf(sqrtf(sn2), EPSN);
  }
}

// ---- Kernel B1: 8 rows/wave-iter (2 sets x 4 rows x 16 lanes), LDS proto ----
__global__ __launch_bounds__(B_THREADS) void simB1_kernel(
    const float* __restrict__ memory, const float* __restrict__ ws,
    float* __restrict__ simAll, int M) {
  __shared__ float sP[WAY * DIM];   // 12.8 KB
  for (int i = threadIdx.x; i < WAY * DIM / 4; i += B_THREADS)
    ((float4*)sP)[i] = ((const float4*)(ws + OFF_PROTO))[i];
  __syncthreads();

  const int lane = threadIdx.x & 63;
  const int sub  = lane & 15;          // 16B-chunk within row
  const int grp  = lane >> 4;          // row within a 4-row set
  const int waveId = blockIdx.x * WPB + (threadIdx.x >> 6);
  const int colOff = sub * 4;
  const float* sPc = sP + colOff;

  for (int base = waveId * RPI; base < M; base += ROWSTRIDE) {
    const int rA = base + grp;          // set A rows: base..base+3
    const int rB = base + 4 + grp;      // set B rows: base+4..base+7
    const bool okA = (rA < M);
    const bool okB = (rB < M);
    const size_t offA = (size_t)(okA ? rA : (M - 1)) * DIM + colOff;
    const size_t offB = (size_t)(okB ? rB : (M - 1)) * DIM + colOff;

    float nA = 0.f, a0 = 0.f, a1 = 0.f, a2 = 0.f, a3 = 0.f, a4 = 0.f;
    float nB = 0.f, b0 = 0.f, b1 = 0.f, b2 = 0.f, b3 = 0.f, b4 = 0.f;
#pragma unroll
    for (int it = 0; it < 10; ++it) {
      const float4 xa = *(const float4*)&memory[offA + it * 64];
      const float4 xb = *(const float4*)&memory[offB + it * 64];
      const float4 p0 = *(const float4*)&sPc[0 * DIM + it * 64];
      const float4 p1 = *(const float4*)&sPc[1 * DIM + it * 64];
      const float4 p2 = *(const float4*)&sPc[2 * DIM + it * 64];
      const float4 p3 = *(const float4*)&sPc[3 * DIM + it * 64];
      const float4 p4 = *(const float4*)&sPc[4 * DIM + it * 64];
      nA = fmaf(xa.x, xa.x, fmaf(xa.y, xa.y, fmaf(xa.z, xa.z, fmaf(xa.w, xa.w, nA))));
      a0 = fmaf(xa.x, p0.x, fmaf(xa.y, p0.y, fmaf(xa.z, p0.z, fmaf(xa.w, p0.w, a0))));
      a1 = fmaf(xa.x, p1.x, fmaf(xa.y, p1.y, fmaf(xa.z, p1.z, fmaf(xa.w, p1.w, a1))));
      a2 = fmaf(xa.x, p2.x, fmaf(xa.y, p2.y, fmaf(xa.z, p2.z, fmaf(xa.w, p2.w, a2))));
      a3 = fmaf(xa.x, p3.x, fmaf(xa.y, p3.y, fmaf(xa.z, p3.z, fmaf(xa.w, p3.w, a3))));
      a4 = fmaf(xa.x, p4.x, fmaf(xa.y, p4.y, fmaf(xa.z, p4.z, fmaf(xa.w, p4.w, a4))));
      nB = fmaf(xb.x, xb.x, fmaf(xb.y, xb.y, fmaf(xb.z, xb.z, fmaf(xb.w, xb.w, nB))));
      b0 = fmaf(xb.x, p0.x, fmaf(xb.y, p0.y, fmaf(xb.z, p0.z, fmaf(xb.w, p0.w, b0))));
      b1 = fmaf(xb.x, p1.x, fmaf(xb.y, p1.y, fmaf(xb.z, p1.z, fmaf(xb.w, p1.w, b1))));
      b2 = fmaf(xb.x, p2.x, fmaf(xb.y, p2.y, fmaf(xb.z, p2.z, fmaf(xb.w, p2.w, b2))));
      b3 = fmaf(xb.x, p3.x, fmaf(xb.y, p3.y, fmaf(xb.z, p3.z, fmaf(xb.w, p3.w, b3))));
      b4 = fmaf(xb.x, p4.x, fmaf(xb.y, p4.y, fmaf(xb.z, p4.z, fmaf(xb.w, p4.w, b4))));
    }

    // 16-lane reductions (independent chains)
    const float rA0 = rowReduce16(a0), rA1 = rowReduce16(a1), rA2 = rowReduce16(a2);
    const float rA3 = rowReduce16(a3), rA4 = rowReduce16(a4), rAn = rowReduce16(nA);
    const float rB0 = rowReduce16(b0), rB1 = rowReduce16(b1), rB2 = rowReduce16(b2);
    const float rB3 = rowReduce16(b3), rB4 = rowReduce16(b4), rBn = rowReduce16(nB);

    const float sA = 0.2f / fmaxf(sqrtf(rAn), EPSN);
    const float sB = 0.2f / fmaxf(sqrtf(rBn), EPSN);
    float vA = rA0, vB = rB0;
    vA = (sub == 1) ? rA1 : vA;  vB = (sub == 1) ? rB1 : vB;
    vA = (sub == 2) ? rA2 : vA;  vB = (sub == 2) ? rB2 : vB;
    vA = (sub == 3) ? rA3 : vA;  vB = (sub == 3) ? rB3 : vB;
    vA = (sub == 4) ? rA4 : vA;  vB = (sub == 4) ? rB4 : vB;
    if (okA && sub < WAY) simAll[(size_t)sub * M + rA] = vA * sA;
    if (okB && sub < WAY) simAll[(size_t)sub * M + rB] = vB * sB;
  }
}

// -------- Kernel C1: per-(way,segment) partial top-16 over simAll ---------
__global__ __launch_bounds__(256) void topkC1_kernel(
    const float* __restrict__ simAll, float* __restrict__ candV,
    int* __restrict__ candI, int M) {
  const int w   = blockIdx.x / SEGS;
  const int seg = blockIdx.x % SEGS;
  const int tid = threadIdx.x;
  const int len = (M + SEGS - 1) / SEGS;
  const int i0 = seg * len;
  const int i1 = min(i0 + len, M);

  float lv[KTOP];
  int   li[KTOP];
#pragma unroll
  for (int k = 0; k < KTOP; ++k) { lv[k] = -FLT_MAX; li[k] = 0; }

  const float* sv = simAll + (size_t)w * M;
  for (int i = i0 + tid; i < i1; i += 256) {
    const float v = sv[i];
    if (v > lv[KTOP - 1]) {
      const int id = SHOT + i;
#pragma unroll
      for (int j = KTOP - 1; j >= 1; --j) {
        const float up = lv[j - 1];
        const int   ui = li[j - 1];
        const bool shift = (up < v);
        const float cur = lv[j];
        const int  curi = li[j];
        lv[j] = shift ? up : (cur < v ? v : cur);
        li[j] = shift ? ui : (cur < v ? id : curi);
      }
      if (lv[0] < v) { li[0] = id; lv[0] = v; }
    }
  }

  __shared__ float sLV[256][KTOP];
  __shared__ int   sLI[256][KTOP];
  __shared__ float sWv[4];
  __shared__ int   sWi[4];
#pragma unroll
  for (int k = 0; k < KTOP; ++k) { sLV[tid][k] = lv[k]; sLI[tid][k] = li[k]; }
  __syncthreads();

  int cursor = 0;
  for (int r = 0; r < KTOP; ++r) {
    float v = (cursor < KTOP) ? sLV[tid][cursor] : -FLT_MAX;
    int   t = tid;
#pragma unroll
    for (int off = 32; off >= 1; off >>= 1) {
      const float ov = __shfl_xor(v, off, 64);
      const int   ot = __shfl_xor(t, off, 64);
      if (ov > v) { v = ov; t = ot; }
    }
    __syncthreads();
    if ((tid & 63) == 0) { sWv[tid >> 6] = v; sWi[tid >> 6] = t; }
    __syncthreads();
    float bv = sWv[0]; int bt = sWi[0];
#pragma unroll
    for (int q = 1; q < 4; ++q)
      if (sWv[q] > bv) { bv = sWv[q]; bt = sWi[q]; }
    if (tid == bt) {
      candV[(size_t)(w * SEGS + seg) * KTOP + r] = sLV[tid][cursor];
      candI[(size_t)(w * SEGS + seg) * KTOP + r] = sLI[tid][cursor];
      ++cursor;
    }
    __syncthreads();
  }
}

// ------- Kernel C2: merge candidates + support -> top-16 -> prototype -----
__global__ __launch_bounds__(256) void topkProtoC2_kernel(
    const float* __restrict__ support, const float* __restrict__ memory,
    float* __restrict__ ws, const float* __restrict__ candV,
    const int* __restrict__ candI, int M) {
  const int w = blockIdx.x;
  const int tid = threadIdx.x;

  float lv[KTOP];
  int   li[KTOP];
#pragma unroll
  for (int k = 0; k < KTOP; ++k) { lv[k] = -FLT_MAX; li[k] = 0; }
  if (tid < SHOT) {
    lv[0] = ws[OFF_SIMSUP + tid * WAY + w];
    li[0] = tid;
  }

  const float* cv = candV + (size_t)w * CANDS;
  const int*   ci = candI + (size_t)w * CANDS;
  for (int i = tid; i < CANDS; i += 256) {
    const float v = cv[i];
    if (v > lv[KTOP - 1]) {
      const int id = ci[i];
#pragma unroll
      for (int j = KTOP - 1; j >= 1; --j) {
        const float up = lv[j - 1];
        const int   ui = li[j - 1];
        const bool shift = (up < v);
        const float cur = lv[j];
        const int  curi = li[j];
        lv[j] = shift ? up : (cur < v ? v : cur);
        li[j] = shift ? ui : (cur < v ? id : curi);
      }
      if (lv[0] < v) { li[0] = id; lv[0] = v; }
    }
  }

  __shared__ float sLV[256][KTOP];
  __shared__ int   sLI[256][KTOP];
  __shared__ float outV[KTOP];
  __shared__ int   outI[KTOP];
  __shared__ float sWv[4];
  __shared__ int   sWi[4];
  __shared__ float sred[4];
#pragma unroll
  for (int k = 0; k < KTOP; ++k) { sLV[tid][k] = lv[k]; sLI[tid][k] = li[k]; }
  __syncthreads();

  int cursor = 0;
  for (int r = 0; r < KTOP; ++r) {
    float v = (cursor < KTOP) ? sLV[tid][cursor] : -FLT_MAX;
    int   t = tid;
#pragma unroll
    for (int off = 32; off >= 1; off >>= 1) {
      const float ov = __shfl_xor(v, off, 64);
      const int   ot = __shfl_xor(t, off, 64);
      if (ov > v) { v = ov; t = ot; }
    }
    __syncthreads();
    if ((tid & 63) == 0) { sWv[tid >> 6] = v; sWi[tid >> 6] = t; }
    __syncthreads();
    float bv = sWv[0]; int bt = sWi[0];
#pragma unroll
    for (int q = 1; q < 4; ++q)
      if (sWv[q] > bv) { bv = sWv[q]; bt = sWi[q]; }
    if (tid == bt) {
      outV[r] = sLV[tid][cursor];
      outI[r] = sLI[tid][cursor];
      ++cursor;
    }
    __syncthreads();
  }

  float sumW = 0.f;
#pragma unroll
  for (int k = 0; k < KTOP; ++k) sumW += outV[k];

  float pw[3];
  float n2 = 0.f;
#pragma unroll
  for (int c = 0; c < 3; ++c) {
    const int t = tid + 256 * c;
    float acc = 0.f;
    if (t < DIM) {
#pragma unroll
      for (int k = 0; k < KTOP; ++k) {
        const int gi = outI[k];
        const float* emb = (gi < SHOT)
            ? (support + (size_t)(gi * WAY + w) * DIM)
            : (memory + (size_t)(gi - SHOT) * DIM);
        acc += outV[k] * emb[t];
      }
      acc /= sumW;
    }
    pw[c] = acc;
    n2 += acc * acc;
  }
  n2 = blockReduce256(n2, sred);
  const float inv = 1.0f / fmaxf(sqrtf(n2), EPSN);
#pragma unroll
  for (int c = 0; c < 3; ++c) {
    const int t = tid + 256 * c;
    if (t < DIM) ws[OFF_PROTOW + w * DIM + t] = pw[c] * inv;
  }
}

// ---------------- Kernel D: logits = q . proto_n / T ----------------------
__global__ __launch_bounds__(64) void logitsD_kernel(
    const float* __restrict__ query, const float* __restrict__ ws,
    float* __restrict__ out) {
  const int q = blockIdx.x;
  const int p = blockIdx.y;
  const int lane = threadIdx.x;
  const float* qr = query + (size_t)q * DIM;
  const float* pn = ws + OFF_PROTOW + p * DIM;
  float acc = 0.f;
#pragma unroll
  for (int k = 0; k < 5; ++k) {
    const float2 a = *(const float2*)&qr[2 * (lane + 64 * k)];
    const float2 b = *(const float2*)&pn[2 * (lane + 64 * k)];
    acc += a.x * b.x + a.y * b.y;
  }
#pragma unroll
  for (int off = 32; off >= 1; off >>= 1) acc += __shfl_xor(acc, off, 64);
  if (lane == 0) out[q * WAY + p] = acc * (1.0f / 64.0f);
}

extern "C" void kernel_launch(void* const* d_in, const int* in_sizes, int n_in,
                              void* d_out, int out_size, void* d_ws, size_t ws_size,
                              hipStream_t stream) {
  const float* support = (const float*)d_in[0];
  const float* query   = (const float*)d_in[1];
  const float* memory  = (const float*)d_in[2];
  float* out = (float*)d_out;
  float* ws  = (float*)d_ws;
  const int M = in_sizes[2] / DIM;

  float* candV  = ws + OFF_CANDV;
  int*   candI  = (int*)(ws + OFF_CANDI);
  float* simAll = ws + OFF_SIM;

  hipLaunchKernelGGL(protoA_kernel, dim3(WAY), dim3(256), 0, stream, support, ws);
  hipLaunchKernelGGL(simB1_kernel, dim3(B_BLOCKS), dim3(B_THREADS), 0, stream,
                     memory, ws, simAll, M);
  hipLaunchKernelGGL(topkC1_kernel, dim3(WAY * SEGS), dim3(256), 0, stream,
                     simAll, candV, candI, M);
  hipLaunchKernelGGL(topkProtoC2_kernel, dim3(WAY), dim3(256), 0, stream,
                     support, memory, ws, candV, candI, M);
  hipLaunchKernelGGL(logitsD_kernel, dim3(75, WAY), dim3(64), 0, stream,
                     query, ws, out);
}